// Round 1
// baseline (1077.531 us; speedup 1.0000x reference)
//
#include <hip/hip_runtime.h>

#define NTOK 32768

// ---------------- init small buffers ----------------
__global__ void k_init(const float* __restrict__ bEF, float* __restrict__ kp,
                       float* __restrict__ vp, float* __restrict__ qd)
{
    int i = blockIdx.x * 256 + threadIdx.x;
    if (i < 8192) { kp[i] = bEF[i & 63]; vp[i] = bEF[i & 63]; }
    if (i < 2048) qd[i] = 0.f;
}

// ---------------- fused LayerNorm + QKVV GEMM ----------------
// qkvv layout: [isel(4)][b(2)][h(4)][d(16)][N]
__global__ __launch_bounds__(256) void k_ln_qkvv(
    const float* __restrict__ x, const float* __restrict__ lnw,
    const float* __restrict__ lnb, const float* __restrict__ Wq,
    float* __restrict__ qkvv)
{
    __shared__ float xt[64][68];
    __shared__ float mu_s[64], rs_s[64];
    int bid = blockIdx.x;
    int b = bid >> 9;
    int n0 = (bid & 511) << 6;
    int tid = threadIdx.x;
    for (int i = tid; i < 4096; i += 256) {
        int c = i >> 6, t = i & 63;
        xt[t][c] = x[(((size_t)(b * 64 + c)) << 15) + n0 + t];
    }
    __syncthreads();
    if (tid < 64) {
        float s = 0.f, s2 = 0.f;
        for (int c = 0; c < 64; ++c) { float v = xt[tid][c]; s += v; s2 += v * v; }
        float mu = s * (1.f / 64.f);
        float var = s2 * (1.f / 64.f) - mu * mu;
        mu_s[tid] = mu;
        rs_s[tid] = rsqrtf(var + 1e-5f);
    }
    __syncthreads();
    for (int i = tid; i < 4096; i += 256) {
        int c = i >> 6, t = i & 63;
        xt[t][c] = (xt[t][c] - mu_s[t]) * rs_s[t] * lnw[c] + lnb[c];
    }
    __syncthreads();
    int co = tid;
    float4 wr[16];
    const float4* wq4 = (const float4*)(Wq + co * 64);
#pragma unroll
    for (int j = 0; j < 16; ++j) wr[j] = wq4[j];
    int isel = co >> 6, h = (co >> 4) & 3, d = co & 15;
    float* outp = qkvv + (size_t)(((isel * 2 + b) * 4 + h) * 16 + d) * NTOK + n0;
    for (int t = 0; t < 64; ++t) {
        const float4* xr = (const float4*)&xt[t][0];
        float a0 = 0, a1 = 0, a2 = 0, a3 = 0;
#pragma unroll
        for (int j = 0; j < 16; ++j) {
            float4 xv = xr[j];
            a0 += wr[j].x * xv.x; a1 += wr[j].y * xv.y;
            a2 += wr[j].z * xv.z; a3 += wr[j].w * xv.w;
        }
        outp[t] = (a0 + a1) + (a2 + a3);
    }
}

// ---------------- L2 norms of q,k over N ----------------
__global__ __launch_bounds__(256) void k_norms(const float* __restrict__ qkvv,
    float* __restrict__ inv_qn, float* __restrict__ inv_kn)
{
    __shared__ float red[256];
    int r = blockIdx.x;          // 0..255 : 0..127 q rows, 128..255 k rows
    int arr = r >> 7;
    int sub = r & 127;
    const float4* p = (const float4*)(qkvv + (size_t)(arr * 128 + sub) * NTOK);
    float s = 0.f;
    int tid = threadIdx.x;
    for (int i = tid; i < NTOK / 4; i += 256) {
        float4 v = p[i];
        s += v.x * v.x + v.y * v.y + v.z * v.z + v.w * v.w;
    }
    red[tid] = s; __syncthreads();
    for (int off = 128; off > 0; off >>= 1) {
        if (tid < off) red[tid] += red[tid + off];
        __syncthreads();
    }
    if (tid == 0) {
        float inv = 1.f / fmaxf(sqrtf(red[0]), 1e-12f);
        (arr == 0 ? inv_qn : inv_kn)[sub] = inv;
    }
}

// ---------------- k_proj / v_proj : [b][h][d][p] += sum_n row[n]*W_EF[p][n] ----------------
__global__ __launch_bounds__(256) void k_proj_kernel(
    const float* __restrict__ qkvv, const float* __restrict__ WEF,
    float* __restrict__ kp, float* __restrict__ vp)
{
    __shared__ float Wl[64][132];
    __shared__ float kl[16][132];
    __shared__ float vl[16][132];
    int kc = blockIdx.x;
    int bh = blockIdx.y;
    int b = bh >> 2, h = bh & 3;
    int tid = threadIdx.x;
    int d_ = tid & 15, pg = tid >> 4;
    float ak[4] = {0, 0, 0, 0}, av[4] = {0, 0, 0, 0};
    const float* kbase = qkvv + (size_t)(((2 + b) * 4 + h) * 16) * NTOK;
    const float* vbase = qkvv + (size_t)(((6 + b) * 4 + h) * 16) * NTOK;
    for (int sub = 0; sub < 4; ++sub) {
        int nb = kc * 512 + sub * 128;
        __syncthreads();
        for (int i = tid; i < 64 * 128; i += 256) {
            int pp = i >> 7, nn = i & 127;
            Wl[pp][nn] = WEF[(size_t)pp * NTOK + nb + nn];
        }
        for (int i = tid; i < 16 * 128; i += 256) {
            int dd = i >> 7, nn = i & 127;
            kl[dd][nn] = kbase[(size_t)dd * NTOK + nb + nn];
            vl[dd][nn] = vbase[(size_t)dd * NTOK + nb + nn];
        }
        __syncthreads();
        for (int n4 = 0; n4 < 32; ++n4) {
            float4 kv = *(const float4*)&kl[d_][n4 * 4];
            float4 vv = *(const float4*)&vl[d_][n4 * 4];
#pragma unroll
            for (int j = 0; j < 4; ++j) {
                float4 wv = *(const float4*)&Wl[pg + j * 16][n4 * 4];
                ak[j] += kv.x * wv.x + kv.y * wv.y + kv.z * wv.z + kv.w * wv.w;
                av[j] += vv.x * wv.x + vv.y * wv.y + vv.z * wv.z + vv.w * wv.w;
            }
        }
    }
    int outbase = ((b * 4 + h) * 16 + d_) * 64;
#pragma unroll
    for (int j = 0; j < 4; ++j) {
        atomicAdd(&kp[outbase + pg + j * 16], ak[j]);
        atomicAdd(&vp[outbase + pg + j * 16], av[j]);
    }
}

// ---------------- channel-attention logits q.k over N ----------------
__global__ __launch_bounds__(256) void k_qdot(
    const float* __restrict__ qkvv, float* __restrict__ qd)
{
    __shared__ float ql[16][132];
    __shared__ float kl[16][132];
    int kc = blockIdx.x; int bh = blockIdx.y;
    int b = bh >> 2, h = bh & 3;
    int tid = threadIdx.x;
    int d_ = tid >> 4, e_ = tid & 15;
    float acc = 0.f;
    const float* qbase = qkvv + (size_t)((b * 4 + h) * 16) * NTOK;
    const float* kbase = qkvv + (size_t)(((2 + b) * 4 + h) * 16) * NTOK;
    for (int sub = 0; sub < 4; ++sub) {
        int nb = kc * 512 + sub * 128;
        __syncthreads();
        for (int i = tid; i < 16 * 128; i += 256) {
            int dd = i >> 7, nn = i & 127;
            ql[dd][nn] = qbase[(size_t)dd * NTOK + nb + nn];
            kl[dd][nn] = kbase[(size_t)dd * NTOK + nb + nn];
        }
        __syncthreads();
        for (int n4 = 0; n4 < 32; ++n4) {
            float4 qv = *(const float4*)&ql[d_][n4 * 4];
            float4 kv = *(const float4*)&kl[e_][n4 * 4];
            acc += qv.x * kv.x + qv.y * kv.y + qv.z * kv.z + qv.w * kv.w;
        }
    }
    atomicAdd(&qd[(bh * 16 + d_) * 16 + e_], acc);
}

// ---------------- channel-attention softmax ----------------
__global__ void k_softmax_ca(const float* __restrict__ qd,
    const float* __restrict__ inv_qn, const float* __restrict__ inv_kn,
    const float* __restrict__ temp1, float* __restrict__ attn)
{
    int r = threadIdx.x;
    if (r >= 128) return;
    int bh = r >> 4;
    int h = bh & 3;
    float iq = inv_qn[r];
    float t1 = temp1[h];
    float sc[16];
    float mx = -1e30f;
#pragma unroll
    for (int e = 0; e < 16; ++e) {
        float v = qd[r * 16 + e] * iq * inv_kn[bh * 16 + e] * t1;
        sc[e] = v; mx = fmaxf(mx, v);
    }
    float s = 0.f;
#pragma unroll
    for (int e = 0; e < 16; ++e) { sc[e] = __expf(sc[e] - mx); s += sc[e]; }
    float inv = 1.f / s;
#pragma unroll
    for (int e = 0; e < 16; ++e) attn[r * 16 + e] = sc[e] * inv;
}

// ---------------- x_ca = attn_ca @ v_ca, stored permuted [b][n][h*16+d] ----------------
__global__ __launch_bounds__(256) void k_xca(
    const float* __restrict__ qkvv, const float* __restrict__ attn,
    float* __restrict__ xca)
{
    __shared__ float al[16][16];
    int bh = blockIdx.y; int b = bh >> 2, h = bh & 3;
    int tid = threadIdx.x;
    al[tid >> 4][tid & 15] = attn[bh * 256 + tid];
    __syncthreads();
    int n = blockIdx.x * 256 + tid;
    const float* vbase = qkvv + (size_t)(((4 + b) * 4 + h) * 16) * NTOK + n;
    float acc[16];
#pragma unroll
    for (int d = 0; d < 16; ++d) acc[d] = 0.f;
#pragma unroll
    for (int e = 0; e < 16; ++e) {
        float va = vbase[(size_t)e * NTOK];
#pragma unroll
        for (int d = 0; d < 16; ++d) acc[d] += al[d][e] * va;
    }
    float* op = xca + ((size_t)(b * NTOK + n)) * 64 + h * 16;
#pragma unroll
    for (int d4 = 0; d4 < 4; ++d4) {
        float4 v; v.x = acc[d4 * 4]; v.y = acc[d4 * 4 + 1];
        v.z = acc[d4 * 4 + 2]; v.w = acc[d4 * 4 + 3];
        *(float4*)&op[d4 * 4] = v;
    }
}

// ---------------- fused spatial attention; x_sa stored as [b][d][h][n] (faithful permute) ---
__global__ __launch_bounds__(256) void k_attn_sa(
    const float* __restrict__ qkvv, const float* __restrict__ inv_qn,
    const float* __restrict__ kp, const float* __restrict__ vp,
    const float* __restrict__ temp2, float* __restrict__ xsa)
{
    __shared__ float kl[16][64];
    __shared__ float vl[16][64];
    __shared__ float iq[16];
    int bh = blockIdx.y; int b = bh >> 2, h = bh & 3;
    int tid = threadIdx.x;
    for (int i = tid; i < 1024; i += 256) {
        kl[i >> 6][i & 63] = kp[bh * 1024 + i];
        vl[i >> 6][i & 63] = vp[bh * 1024 + i];
    }
    if (tid < 16) iq[tid] = inv_qn[bh * 16 + tid];
    __syncthreads();
    int n = blockIdx.x * 256 + tid;
    const float* qbase = qkvv + (size_t)(bh * 16) * NTOK + n;
    float qn_[16];
#pragma unroll
    for (int d = 0; d < 16; ++d) qn_[d] = qbase[(size_t)d * NTOK] * iq[d];
    float t2 = temp2[h];
    float sc[64];
#pragma unroll
    for (int p = 0; p < 64; ++p) sc[p] = 0.f;
#pragma unroll
    for (int d = 0; d < 16; ++d) {
        float qv = qn_[d];
        const float4* kr = (const float4*)&kl[d][0];
#pragma unroll
        for (int p4 = 0; p4 < 16; ++p4) {
            float4 kv = kr[p4];
            sc[p4 * 4 + 0] += qv * kv.x; sc[p4 * 4 + 1] += qv * kv.y;
            sc[p4 * 4 + 2] += qv * kv.z; sc[p4 * 4 + 3] += qv * kv.w;
        }
    }
    float mx = -1e30f;
#pragma unroll
    for (int p = 0; p < 64; ++p) { sc[p] *= t2; mx = fmaxf(mx, sc[p]); }
    float s = 0.f;
#pragma unroll
    for (int p = 0; p < 64; ++p) { sc[p] = __expf(sc[p] - mx); s += sc[p]; }
    float inv = 1.f / s;
#pragma unroll
    for (int p = 0; p < 64; ++p) sc[p] *= inv;
    float* ob = xsa + (size_t)b * 2097152 + n;
#pragma unroll
    for (int d = 0; d < 16; ++d) {
        const float4* vr = (const float4*)&vl[d][0];
        float a0 = 0, a1 = 0, a2 = 0, a3 = 0;
#pragma unroll
        for (int p4 = 0; p4 < 16; ++p4) {
            float4 vv = vr[p4];
            a0 += sc[p4 * 4] * vv.x; a1 += sc[p4 * 4 + 1] * vv.y;
            a2 += sc[p4 * 4 + 2] * vv.z; a3 += sc[p4 * 4 + 3] * vv.w;
        }
        ob[(size_t)(d * 4 + h) * NTOK] = (a0 + a1) + (a2 + a3);
    }
}

// ---------------- EPA epilogue: proj + gamma + residual -> attn_skip [b][c][n] ----------------
__global__ __launch_bounds__(256) void k_epilogue(
    const float* __restrict__ x, const float* __restrict__ xsa,
    const float* __restrict__ xca, const float* __restrict__ Wo1,
    const float* __restrict__ bo1, const float* __restrict__ Wo2,
    const float* __restrict__ bo2, const float* __restrict__ gamma,
    float* __restrict__ attn_skip)
{
    __shared__ float W1[32][64];
    __shared__ float W2[32][64];
    int tid = threadIdx.x;
    for (int i = tid; i < 2048; i += 256) {
        W1[i >> 6][i & 63] = Wo1[i];
        W2[i >> 6][i & 63] = Wo2[i];
    }
    __syncthreads();
    int bid = blockIdx.x;
    int b = bid >> 9;
    int n0 = (bid & 511) << 6;
    int t = tid & 63, cg = tid >> 6;
    int n = n0 + t;
    const float* row = (cg < 2) ? xsa + (size_t)b * 2097152 + (size_t)n * 64
                                : xca + ((size_t)(b * NTOK + n)) * 64;
    const float* Wb = (cg < 2) ? &W1[(cg & 1) * 16][0] : &W2[(cg & 1) * 16][0];
    const float* bias = (cg < 2) ? bo1 + (cg & 1) * 16 : bo2 + (cg & 1) * 16;
    float acc[16];
#pragma unroll
    for (int j = 0; j < 16; ++j) acc[j] = 0.f;
    const float4* r4 = (const float4*)row;
#pragma unroll
    for (int c4 = 0; c4 < 16; ++c4) {
        float4 rv = r4[c4];
#pragma unroll
        for (int j = 0; j < 16; ++j) {
            float4 wv = *(const float4*)&Wb[j * 64 + c4 * 4];
            acc[j] += rv.x * wv.x + rv.y * wv.y + rv.z * wv.z + rv.w * wv.w;
        }
    }
#pragma unroll
    for (int j = 0; j < 16; ++j) {
        int c = cg * 16 + j;
        size_t idx = (((size_t)(b * 64 + c)) << 15) + n;
        attn_skip[idx] = x[idx] + gamma[c] * (acc[j] + bias[j]);
    }
}

// ---------------- direct 3x3x3 conv + BN(eval) [+skip] + LReLU ----------------
// MODE 0: out = lrelu(bn1(conv(in)));  MODE 1: out = lrelu(bn2(conv(in)) + skip)
template <int MODE>
__global__ __launch_bounds__(256) void k_conv3(
    const float* __restrict__ in, const float* __restrict__ w,
    const float* __restrict__ bnw, const float* __restrict__ bnb,
    const float* __restrict__ skip, float* __restrict__ out)
{
    __shared__ float inl[4][6][6][36];
    __shared__ float wl[4][27][8];
    int bx = blockIdx.x;
    int ocg = bx & 7;
    int b = (bx >> 3) & 1;
    int yt = (bx >> 4) & 7;
    int zt = bx >> 7;
    int tid = threadIdx.x;
    int xx_ = tid & 31, part = tid >> 5;
    int zy0 = part * 2, zy1 = part * 2 + 1;
    int z0 = zy0 >> 2, y0 = zy0 & 3;
    int z1 = zy1 >> 2, y1 = zy1 & 3;
    float acc0[8], acc1[8];
#pragma unroll
    for (int j = 0; j < 8; ++j) { acc0[j] = 0.f; acc1[j] = 0.f; }
    for (int ic0 = 0; ic0 < 64; ic0 += 4) {
        __syncthreads();
        for (int i = tid; i < 4 * 6 * 6 * 36; i += 256) {
            int xi = i % 36;
            int r = i / 36;
            int yy = r % 6; r /= 6;
            int zz = r % 6; int ic = r / 6;
            int gz = zt * 4 + zz - 1, gy = yt * 4 + yy - 1, gx = xi - 1;
            float v = 0.f;
            if (gz >= 0 && gz < 32 && gy >= 0 && gy < 32 && gx >= 0 && gx < 32)
                v = in[(((size_t)(b * 64 + ic0 + ic)) << 15) + ((gz * 32 + gy) * 32 + gx)];
            inl[ic][zz][yy][xi] = v;
        }
        for (int i = tid; i < 864; i += 256) {
            int oc = i & 7;
            int r = i >> 3;
            int tap = r % 27; int ic = r / 27;
            wl[ic][tap][oc] = w[((size_t)(ocg * 8 + oc) * 64 + ic0 + ic) * 27 + tap];
        }
        __syncthreads();
#pragma unroll
        for (int ic = 0; ic < 4; ++ic) {
            float r0[27], r1[27];
#pragma unroll
            for (int kz = 0; kz < 3; ++kz)
#pragma unroll
                for (int ky = 0; ky < 3; ++ky)
#pragma unroll
                    for (int kx = 0; kx < 3; ++kx) {
                        r0[(kz * 3 + ky) * 3 + kx] = inl[ic][z0 + kz][y0 + ky][xx_ + kx];
                        r1[(kz * 3 + ky) * 3 + kx] = inl[ic][z1 + kz][y1 + ky][xx_ + kx];
                    }
#pragma unroll
            for (int tap = 0; tap < 27; ++tap) {
                float4 wa = *(const float4*)&wl[ic][tap][0];
                float4 wb = *(const float4*)&wl[ic][tap][4];
                float p0 = r0[tap], p1 = r1[tap];
                acc0[0] += p0 * wa.x; acc0[1] += p0 * wa.y; acc0[2] += p0 * wa.z; acc0[3] += p0 * wa.w;
                acc0[4] += p0 * wb.x; acc0[5] += p0 * wb.y; acc0[6] += p0 * wb.z; acc0[7] += p0 * wb.w;
                acc1[0] += p1 * wa.x; acc1[1] += p1 * wa.y; acc1[2] += p1 * wa.z; acc1[3] += p1 * wa.w;
                acc1[4] += p1 * wb.x; acc1[5] += p1 * wb.y; acc1[6] += p1 * wb.z; acc1[7] += p1 * wb.w;
            }
        }
    }
    int gz0 = zt * 4 + z0, gy0 = yt * 4 + y0;
    int gz1 = zt * 4 + z1, gy1 = yt * 4 + y1;
    float rb = rsqrtf(1.f + 1e-5f);
#pragma unroll
    for (int j = 0; j < 8; ++j) {
        int oc = ocg * 8 + j;
        float scale = bnw[oc] * rb;
        float sh = bnb[oc];
        size_t base = ((size_t)(b * 64 + oc)) << 15;
        size_t i0 = base + (gz0 * 32 + gy0) * 32 + xx_;
        size_t i1 = base + (gz1 * 32 + gy1) * 32 + xx_;
        float v0 = acc0[j] * scale + sh;
        float v1 = acc1[j] * scale + sh;
        if (MODE == 1) { v0 += skip[i0]; v1 += skip[i1]; }
        v0 = v0 >= 0.f ? v0 : 0.01f * v0;
        v1 = v1 >= 0.f ? v1 : 0.01f * v1;
        out[i0] = v0; out[i1] = v1;
    }
}

// ---------------- conv8 (1x1x1) + bias + final residual, in-place on d_out ----------------
__global__ __launch_bounds__(256) void k_conv8(
    const float* __restrict__ in2, const float* __restrict__ w8,
    const float* __restrict__ b8, float* __restrict__ io)
{
    __shared__ float wl[64][64];   // [ci][c]
    int tid = threadIdx.x;
    for (int i = tid; i < 4096; i += 256) {
        int c = i & 63, ci = i >> 6;
        wl[ci][c] = w8[c * 64 + ci];
    }
    __syncthreads();
    int bidx = blockIdx.x;
    int b = bidx >> 7;
    int n = ((bidx & 127) << 8) + tid;
    float acc[64];
#pragma unroll
    for (int c = 0; c < 64; ++c) acc[c] = 0.f;
    const float* ip = in2 + (((size_t)b) << 21) + n;
    for (int ci = 0; ci < 64; ++ci) {
        float v = ip[(size_t)ci << 15];
        const float4* wr = (const float4*)&wl[ci][0];
#pragma unroll
        for (int c4 = 0; c4 < 16; ++c4) {
            float4 wv = wr[c4];
            acc[c4 * 4 + 0] += v * wv.x; acc[c4 * 4 + 1] += v * wv.y;
            acc[c4 * 4 + 2] += v * wv.z; acc[c4 * 4 + 3] += v * wv.w;
        }
    }
    float* op = io + (((size_t)b) << 21) + n;
#pragma unroll
    for (int c = 0; c < 64; ++c) {
        size_t idx = (size_t)c << 15;
        op[idx] = op[idx] + b8[c] + acc[c];
    }
}

extern "C" void kernel_launch(void* const* d_in, const int* in_sizes, int n_in,
                              void* d_out, int out_size, void* d_ws, size_t ws_size,
                              hipStream_t stream) {
    const float* x      = (const float*)d_in[0];
    const float* ln_w   = (const float*)d_in[1];
    const float* ln_b   = (const float*)d_in[2];
    const float* gamma  = (const float*)d_in[3];
    const float* temp1  = (const float*)d_in[4];
    const float* temp2  = (const float*)d_in[5];
    const float* W_qkvv = (const float*)d_in[6];
    const float* W_EF   = (const float*)d_in[7];
    const float* b_EF   = (const float*)d_in[8];
    const float* W_o1   = (const float*)d_in[9];
    const float* b_o1   = (const float*)d_in[10];
    const float* W_o2   = (const float*)d_in[11];
    const float* b_o2   = (const float*)d_in[12];
    const float* conv1w = (const float*)d_in[13];
    const float* conv2w = (const float*)d_in[14];
    const float* bn1_w  = (const float*)d_in[15];
    const float* bn1_b  = (const float*)d_in[16];
    const float* bn2_w  = (const float*)d_in[17];
    const float* bn2_b  = (const float*)d_in[18];
    const float* conv8w = (const float*)d_in[19];
    const float* conv8b = (const float*)d_in[20];

    float* ws   = (float*)d_ws;
    float* qkvv = ws;                        // 16777216 floats
    float* buf1 = qkvv + 16777216;           // 4194304 (x_ca_perm, then out1)
    float* buf2 = buf1 + 4194304;            // 4194304 (x_sa_store, then out2)
    float* kp   = buf2 + 4194304;            // 8192
    float* vp   = kp + 8192;                 // 8192
    float* qd   = vp + 8192;                 // 2048
    float* a_ca = qd + 2048;                 // 2048
    float* iqn  = a_ca + 2048;               // 128
    float* ikn  = iqn + 128;                 // 128

    float* attn_skip = (float*)d_out;        // d_out doubles as attn_skip storage

    hipLaunchKernelGGL(k_init, dim3(32), dim3(256), 0, stream, b_EF, kp, vp, qd);
    hipLaunchKernelGGL(k_ln_qkvv, dim3(1024), dim3(256), 0, stream,
                       x, ln_w, ln_b, W_qkvv, qkvv);
    hipLaunchKernelGGL(k_norms, dim3(256), dim3(256), 0, stream, qkvv, iqn, ikn);
    hipLaunchKernelGGL(k_proj_kernel, dim3(64, 8), dim3(256), 0, stream,
                       qkvv, W_EF, kp, vp);
    hipLaunchKernelGGL(k_qdot, dim3(64, 8), dim3(256), 0, stream, qkvv, qd);
    hipLaunchKernelGGL(k_softmax_ca, dim3(1), dim3(128), 0, stream,
                       qd, iqn, ikn, temp1, a_ca);
    hipLaunchKernelGGL(k_xca, dim3(128, 8), dim3(256), 0, stream, qkvv, a_ca, buf1);
    hipLaunchKernelGGL(k_attn_sa, dim3(128, 8), dim3(256), 0, stream,
                       qkvv, iqn, kp, vp, temp2, buf2);
    hipLaunchKernelGGL(k_epilogue, dim3(1024), dim3(256), 0, stream,
                       x, buf2, buf1, W_o1, b_o1, W_o2, b_o2, gamma, attn_skip);
    hipLaunchKernelGGL((k_conv3<0>), dim3(1024), dim3(256), 0, stream,
                       attn_skip, conv1w, bn1_w, bn1_b, (const float*)nullptr, buf1);
    hipLaunchKernelGGL((k_conv3<1>), dim3(1024), dim3(256), 0, stream,
                       buf1, conv2w, bn2_w, bn2_b, attn_skip, buf2);
    hipLaunchKernelGGL(k_conv8, dim3(256), dim3(256), 0, stream,
                       buf2, conv8w, conv8b, attn_skip);
}

// Round 2
// 453.217 us; speedup vs baseline: 2.3775x; 2.3775x over previous
//
#include <hip/hip_runtime.h>

#define NTOK 32768

typedef __attribute__((ext_vector_type(8))) short short8;
typedef __attribute__((ext_vector_type(4))) float f32x4;

__device__ __forceinline__ short f2b(float f) {
    union { float f; unsigned u; } v; v.f = f;
    unsigned r = v.u + 0x7fffu + ((v.u >> 16) & 1u);
    return (short)(r >> 16);
}

// ---------------- init small buffers ----------------
__global__ void k_init(const float* __restrict__ bEF, float* __restrict__ kp,
                       float* __restrict__ vp, float* __restrict__ qd)
{
    int i = blockIdx.x * 256 + threadIdx.x;
    if (i < 8192) { kp[i] = bEF[i & 63]; vp[i] = bEF[i & 63]; }
    if (i < 2048) qd[i] = 0.f;
}

// ---------------- repack conv weights [oc][ic][27] fp32 -> [tap][oc][ic] bf16 ----------------
__global__ void k_repack(const float* __restrict__ w1, const float* __restrict__ w2,
                         short* __restrict__ wb1, short* __restrict__ wb2)
{
    int i = blockIdx.x * 256 + threadIdx.x;
    if (i >= 221184) return;
    int sel = i >= 110592;
    int j = sel ? i - 110592 : i;
    int tap = j >> 12;
    int r = j & 4095;
    int oc = r >> 6, ic = r & 63;
    const float* w = sel ? w2 : w1;
    short* o = sel ? wb2 : wb1;
    o[j] = f2b(w[(oc * 64 + ic) * 27 + tap]);
}

// ---------------- fused LayerNorm + QKVV GEMM ----------------
// qkvv layout: [isel(4)][b(2)][h(4)][d(16)][N]
__global__ __launch_bounds__(256) void k_ln_qkvv(
    const float* __restrict__ x, const float* __restrict__ lnw,
    const float* __restrict__ lnb, const float* __restrict__ Wq,
    float* __restrict__ qkvv)
{
    __shared__ float xt[64][68];
    __shared__ float mu_s[64], rs_s[64];
    int bid = blockIdx.x;
    int b = bid >> 9;
    int n0 = (bid & 511) << 6;
    int tid = threadIdx.x;
    for (int i = tid; i < 4096; i += 256) {
        int c = i >> 6, t = i & 63;
        xt[t][c] = x[(((size_t)(b * 64 + c)) << 15) + n0 + t];
    }
    __syncthreads();
    if (tid < 64) {
        float s = 0.f, s2 = 0.f;
        for (int c = 0; c < 64; ++c) { float v = xt[tid][c]; s += v; s2 += v * v; }
        float mu = s * (1.f / 64.f);
        float var = s2 * (1.f / 64.f) - mu * mu;
        mu_s[tid] = mu;
        rs_s[tid] = rsqrtf(var + 1e-5f);
    }
    __syncthreads();
    for (int i = tid; i < 4096; i += 256) {
        int c = i >> 6, t = i & 63;
        xt[t][c] = (xt[t][c] - mu_s[t]) * rs_s[t] * lnw[c] + lnb[c];
    }
    __syncthreads();
    int co = tid;
    float4 wr[16];
    const float4* wq4 = (const float4*)(Wq + co * 64);
#pragma unroll
    for (int j = 0; j < 16; ++j) wr[j] = wq4[j];
    int isel = co >> 6, h = (co >> 4) & 3, d = co & 15;
    float* outp = qkvv + (size_t)(((isel * 2 + b) * 4 + h) * 16 + d) * NTOK + n0;
    for (int t = 0; t < 64; ++t) {
        const float4* xr = (const float4*)&xt[t][0];
        float a0 = 0, a1 = 0, a2 = 0, a3 = 0;
#pragma unroll
        for (int j = 0; j < 16; ++j) {
            float4 xv = xr[j];
            a0 += wr[j].x * xv.x; a1 += wr[j].y * xv.y;
            a2 += wr[j].z * xv.z; a3 += wr[j].w * xv.w;
        }
        outp[t] = (a0 + a1) + (a2 + a3);
    }
}

// ---------------- L2 norms of q,k over N ----------------
__global__ __launch_bounds__(256) void k_norms(const float* __restrict__ qkvv,
    float* __restrict__ inv_qn, float* __restrict__ inv_kn)
{
    __shared__ float red[256];
    int r = blockIdx.x;
    int arr = r >> 7;
    int sub = r & 127;
    const float4* p = (const float4*)(qkvv + (size_t)(arr * 128 + sub) * NTOK);
    float s = 0.f;
    int tid = threadIdx.x;
    for (int i = tid; i < NTOK / 4; i += 256) {
        float4 v = p[i];
        s += v.x * v.x + v.y * v.y + v.z * v.z + v.w * v.w;
    }
    red[tid] = s; __syncthreads();
    for (int off = 128; off > 0; off >>= 1) {
        if (tid < off) red[tid] += red[tid + off];
        __syncthreads();
    }
    if (tid == 0) {
        float inv = 1.f / fmaxf(sqrtf(red[0]), 1e-12f);
        (arr == 0 ? inv_qn : inv_kn)[sub] = inv;
    }
}

// ---------------- k_proj / v_proj ----------------
__global__ __launch_bounds__(256) void k_proj_kernel(
    const float* __restrict__ qkvv, const float* __restrict__ WEF,
    float* __restrict__ kp, float* __restrict__ vp)
{
    __shared__ float Wl[64][132];
    __shared__ float kl[16][132];
    __shared__ float vl[16][132];
    int kc = blockIdx.x;
    int bh = blockIdx.y;
    int b = bh >> 2, h = bh & 3;
    int tid = threadIdx.x;
    int d_ = tid & 15, pg = tid >> 4;
    float ak[4] = {0, 0, 0, 0}, av[4] = {0, 0, 0, 0};
    const float* kbase = qkvv + (size_t)(((2 + b) * 4 + h) * 16) * NTOK;
    const float* vbase = qkvv + (size_t)(((6 + b) * 4 + h) * 16) * NTOK;
    for (int sub = 0; sub < 4; ++sub) {
        int nb = kc * 512 + sub * 128;
        __syncthreads();
        for (int i = tid; i < 64 * 128; i += 256) {
            int pp = i >> 7, nn = i & 127;
            Wl[pp][nn] = WEF[(size_t)pp * NTOK + nb + nn];
        }
        for (int i = tid; i < 16 * 128; i += 256) {
            int dd = i >> 7, nn = i & 127;
            kl[dd][nn] = kbase[(size_t)dd * NTOK + nb + nn];
            vl[dd][nn] = vbase[(size_t)dd * NTOK + nb + nn];
        }
        __syncthreads();
        for (int n4 = 0; n4 < 32; ++n4) {
            float4 kv = *(const float4*)&kl[d_][n4 * 4];
            float4 vv = *(const float4*)&vl[d_][n4 * 4];
#pragma unroll
            for (int j = 0; j < 4; ++j) {
                float4 wv = *(const float4*)&Wl[pg + j * 16][n4 * 4];
                ak[j] += kv.x * wv.x + kv.y * wv.y + kv.z * wv.z + kv.w * wv.w;
                av[j] += vv.x * wv.x + vv.y * wv.y + vv.z * wv.z + vv.w * wv.w;
            }
        }
    }
    int outbase = ((b * 4 + h) * 16 + d_) * 64;
#pragma unroll
    for (int j = 0; j < 4; ++j) {
        atomicAdd(&kp[outbase + pg + j * 16], ak[j]);
        atomicAdd(&vp[outbase + pg + j * 16], av[j]);
    }
}

// ---------------- channel-attention logits ----------------
__global__ __launch_bounds__(256) void k_qdot(
    const float* __restrict__ qkvv, float* __restrict__ qd)
{
    __shared__ float ql[16][132];
    __shared__ float kl[16][132];
    int kc = blockIdx.x; int bh = blockIdx.y;
    int b = bh >> 2, h = bh & 3;
    int tid = threadIdx.x;
    int d_ = tid >> 4, e_ = tid & 15;
    float acc = 0.f;
    const float* qbase = qkvv + (size_t)((b * 4 + h) * 16) * NTOK;
    const float* kbase = qkvv + (size_t)(((2 + b) * 4 + h) * 16) * NTOK;
    for (int sub = 0; sub < 4; ++sub) {
        int nb = kc * 512 + sub * 128;
        __syncthreads();
        for (int i = tid; i < 16 * 128; i += 256) {
            int dd = i >> 7, nn = i & 127;
            ql[dd][nn] = qbase[(size_t)dd * NTOK + nb + nn];
            kl[dd][nn] = kbase[(size_t)dd * NTOK + nb + nn];
        }
        __syncthreads();
        for (int n4 = 0; n4 < 32; ++n4) {
            float4 qv = *(const float4*)&ql[d_][n4 * 4];
            float4 kv = *(const float4*)&kl[e_][n4 * 4];
            acc += qv.x * kv.x + qv.y * kv.y + qv.z * kv.z + qv.w * kv.w;
        }
    }
    atomicAdd(&qd[(bh * 16 + d_) * 16 + e_], acc);
}

// ---------------- channel-attention softmax ----------------
__global__ void k_softmax_ca(const float* __restrict__ qd,
    const float* __restrict__ inv_qn, const float* __restrict__ inv_kn,
    const float* __restrict__ temp1, float* __restrict__ attn)
{
    int r = threadIdx.x;
    if (r >= 128) return;
    int bh = r >> 4;
    int h = bh & 3;
    float iq = inv_qn[r];
    float t1 = temp1[h];
    float sc[16];
    float mx = -1e30f;
#pragma unroll
    for (int e = 0; e < 16; ++e) {
        float v = qd[r * 16 + e] * iq * inv_kn[bh * 16 + e] * t1;
        sc[e] = v; mx = fmaxf(mx, v);
    }
    float s = 0.f;
#pragma unroll
    for (int e = 0; e < 16; ++e) { sc[e] = __expf(sc[e] - mx); s += sc[e]; }
    float inv = 1.f / s;
#pragma unroll
    for (int e = 0; e < 16; ++e) attn[r * 16 + e] = sc[e] * inv;
}

// ---------------- x_ca ----------------
__global__ __launch_bounds__(256) void k_xca(
    const float* __restrict__ qkvv, const float* __restrict__ attn,
    float* __restrict__ xca)
{
    __shared__ float al[16][16];
    int bh = blockIdx.y; int b = bh >> 2, h = bh & 3;
    int tid = threadIdx.x;
    al[tid >> 4][tid & 15] = attn[bh * 256 + tid];
    __syncthreads();
    int n = blockIdx.x * 256 + tid;
    const float* vbase = qkvv + (size_t)(((4 + b) * 4 + h) * 16) * NTOK + n;
    float acc[16];
#pragma unroll
    for (int d = 0; d < 16; ++d) acc[d] = 0.f;
#pragma unroll
    for (int e = 0; e < 16; ++e) {
        float va = vbase[(size_t)e * NTOK];
#pragma unroll
        for (int d = 0; d < 16; ++d) acc[d] += al[d][e] * va;
    }
    float* op = xca + ((size_t)(b * NTOK + n)) * 64 + h * 16;
#pragma unroll
    for (int d4 = 0; d4 < 4; ++d4) {
        float4 v; v.x = acc[d4 * 4]; v.y = acc[d4 * 4 + 1];
        v.z = acc[d4 * 4 + 2]; v.w = acc[d4 * 4 + 3];
        *(float4*)&op[d4 * 4] = v;
    }
}

// ---------------- fused spatial attention ----------------
__global__ __launch_bounds__(256) void k_attn_sa(
    const float* __restrict__ qkvv, const float* __restrict__ inv_qn,
    const float* __restrict__ kp, const float* __restrict__ vp,
    const float* __restrict__ temp2, float* __restrict__ xsa)
{
    __shared__ float kl[16][64];
    __shared__ float vl[16][64];
    __shared__ float iq[16];
    int bh = blockIdx.y; int b = bh >> 2, h = bh & 3;
    int tid = threadIdx.x;
    for (int i = tid; i < 1024; i += 256) {
        kl[i >> 6][i & 63] = kp[bh * 1024 + i];
        vl[i >> 6][i & 63] = vp[bh * 1024 + i];
    }
    if (tid < 16) iq[tid] = inv_qn[bh * 16 + tid];
    __syncthreads();
    int n = blockIdx.x * 256 + tid;
    const float* qbase = qkvv + (size_t)(bh * 16) * NTOK + n;
    float qn_[16];
#pragma unroll
    for (int d = 0; d < 16; ++d) qn_[d] = qbase[(size_t)d * NTOK] * iq[d];
    float t2 = temp2[h];
    float sc[64];
#pragma unroll
    for (int p = 0; p < 64; ++p) sc[p] = 0.f;
#pragma unroll
    for (int d = 0; d < 16; ++d) {
        float qv = qn_[d];
        const float4* kr = (const float4*)&kl[d][0];
#pragma unroll
        for (int p4 = 0; p4 < 16; ++p4) {
            float4 kv = kr[p4];
            sc[p4 * 4 + 0] += qv * kv.x; sc[p4 * 4 + 1] += qv * kv.y;
            sc[p4 * 4 + 2] += qv * kv.z; sc[p4 * 4 + 3] += qv * kv.w;
        }
    }
    float mx = -1e30f;
#pragma unroll
    for (int p = 0; p < 64; ++p) { sc[p] *= t2; mx = fmaxf(mx, sc[p]); }
    float s = 0.f;
#pragma unroll
    for (int p = 0; p < 64; ++p) { sc[p] = __expf(sc[p] - mx); s += sc[p]; }
    float inv = 1.f / s;
#pragma unroll
    for (int p = 0; p < 64; ++p) sc[p] *= inv;
    float* ob = xsa + (size_t)b * 2097152 + n;
#pragma unroll
    for (int d = 0; d < 16; ++d) {
        const float4* vr = (const float4*)&vl[d][0];
        float a0 = 0, a1 = 0, a2 = 0, a3 = 0;
#pragma unroll
        for (int p4 = 0; p4 < 16; ++p4) {
            float4 vv = vr[p4];
            a0 += sc[p4 * 4] * vv.x; a1 += sc[p4 * 4 + 1] * vv.y;
            a2 += sc[p4 * 4 + 2] * vv.z; a3 += sc[p4 * 4 + 3] * vv.w;
        }
        ob[(size_t)(d * 4 + h) * NTOK] = (a0 + a1) + (a2 + a3);
    }
}

// ---------------- EPA epilogue: proj + gamma + residual -> attn_skip (fp32 NCHW) + gA (bf16 NHWC)
__global__ __launch_bounds__(256) void k_epilogue(
    const float* __restrict__ x, const float* __restrict__ xsa,
    const float* __restrict__ xca, const float* __restrict__ Wo1,
    const float* __restrict__ bo1, const float* __restrict__ Wo2,
    const float* __restrict__ bo2, const float* __restrict__ gamma,
    float* __restrict__ attn_skip, short* __restrict__ gA)
{
    __shared__ float W1[32][64];
    __shared__ float W2[32][64];
    int tid = threadIdx.x;
    for (int i = tid; i < 2048; i += 256) {
        W1[i >> 6][i & 63] = Wo1[i];
        W2[i >> 6][i & 63] = Wo2[i];
    }
    __syncthreads();
    int bid = blockIdx.x;
    int b = bid >> 9;
    int n0 = (bid & 511) << 6;
    int t = tid & 63, cg = tid >> 6;
    int n = n0 + t;
    const float* row = (cg < 2) ? xsa + (size_t)b * 2097152 + (size_t)n * 64
                                : xca + ((size_t)(b * NTOK + n)) * 64;
    const float* Wb = (cg < 2) ? &W1[(cg & 1) * 16][0] : &W2[(cg & 1) * 16][0];
    const float* bias = (cg < 2) ? bo1 + (cg & 1) * 16 : bo2 + (cg & 1) * 16;
    float acc[16];
#pragma unroll
    for (int j = 0; j < 16; ++j) acc[j] = 0.f;
    const float4* r4 = (const float4*)row;
#pragma unroll
    for (int c4 = 0; c4 < 16; ++c4) {
        float4 rv = r4[c4];
#pragma unroll
        for (int j = 0; j < 16; ++j) {
            float4 wv = *(const float4*)&Wb[j * 64 + c4 * 4];
            acc[j] += rv.x * wv.x + rv.y * wv.y + rv.z * wv.z + rv.w * wv.w;
        }
    }
    float vals[16];
#pragma unroll
    for (int j = 0; j < 16; ++j) {
        int c = cg * 16 + j;
        size_t idx = (((size_t)(b * 64 + c)) << 15) + n;
        float v = x[idx] + gamma[c] * (acc[j] + bias[j]);
        attn_skip[idx] = v;
        vals[j] = v;
    }
    short8 lo, hi;
#pragma unroll
    for (int j = 0; j < 8; ++j) { lo[j] = f2b(vals[j]); hi[j] = f2b(vals[j + 8]); }
    short* gp = gA + ((size_t)(b * NTOK + n)) * 64 + cg * 16;
    *(short8*)&gp[0] = lo;
    *(short8*)&gp[8] = hi;
}

// ---------------- MFMA implicit-GEMM 3x3x3 conv ----------------
// Input: NHWC bf16 gin[b][zyx][64ic]. Weights: wb[tap][oc][ic] bf16.
// MODE 0: out = lrelu(bn1(conv))          -> goutS NHWC bf16
// MODE 1: out = lrelu(bn2(conv) + skip)   -> goutF NCHW fp32
template <int MODE>
__global__ __launch_bounds__(256) void k_conv3m(
    const short* __restrict__ gin, const short* __restrict__ wb,
    const float* __restrict__ bnw, const float* __restrict__ bnb,
    const float* __restrict__ skip, short* __restrict__ goutS,
    float* __restrict__ goutF)
{
    __shared__ __align__(16) short inl_s[24480];   // [3z][6y][34x][40 icpad]
    __shared__ __align__(16) short wl_s[2][2560];  // [64 oc][40 icpad]
    int bx = blockIdx.x;
    int bb = bx >> 8;
    int z0 = (bx >> 3) & 31;
    int y0 = (bx & 7) * 4;
    int tid = threadIdx.x;
    int lane = tid & 63, wv = tid >> 6;
    int l15 = lane & 15, quad = lane >> 4;
    int wo = tid >> 2, wq = tid & 3;

    f32x4 acc[2][4];
#pragma unroll
    for (int s = 0; s < 2; ++s)
#pragma unroll
        for (int nt = 0; nt < 4; ++nt) acc[s][nt] = (f32x4){0.f, 0.f, 0.f, 0.f};

    int boff[4];
#pragma unroll
    for (int nt = 0; nt < 4; ++nt) boff[nt] = (nt * 16 + l15) * 40 + quad * 8;

    for (int chunk = 0; chunk < 2; ++chunk) {
        __syncthreads();
        // stage input halo tile (3*6*34 positions x 32 ic), zero-filled OOB
        for (int i = tid; i < 2448; i += 256) {
            int p = i >> 2, icq = i & 3;
            int xi = p % 34; int t2 = p / 34; int yi = t2 % 6; int zi = t2 / 6;
            int gz = z0 + zi - 1, gy = y0 + yi - 1, gx = xi - 1;
            short8 v = {0, 0, 0, 0, 0, 0, 0, 0};
            if ((unsigned)gz < 32u && (unsigned)gy < 32u && (unsigned)gx < 32u)
                v = *(const short8*)&gin[((size_t)(bb * NTOK + gz * 1024 + gy * 32 + gx)) * 64 + chunk * 32 + icq * 8];
            *(short8*)&inl_s[p * 40 + icq * 8] = v;
        }
        short8 wreg = *(const short8*)&wb[(size_t)wo * 64 + chunk * 32 + wq * 8];
        for (int tap = 0; tap < 27; ++tap) {
            *(short8*)&wl_s[tap & 1][wo * 40 + wq * 8] = wreg;
            if (tap < 26)
                wreg = *(const short8*)&wb[(size_t)((tap + 1) * 64 + wo) * 64 + chunk * 32 + wq * 8];
            __syncthreads();
            int kz = tap / 9, ky = (tap / 3) % 3, kx = tap % 3;
            const short* wlb = wl_s[tap & 1];
            short8 bf[4];
#pragma unroll
            for (int nt = 0; nt < 4; ++nt) bf[nt] = *(const short8*)&wlb[boff[nt]];
            int rowb = (kz * 6 + wv + ky) * 34;
#pragma unroll
            for (int s = 0; s < 2; ++s) {
                short8 af = *(const short8*)&inl_s[(rowb + s * 16 + l15 + kx) * 40 + quad * 8];
#pragma unroll
                for (int nt = 0; nt < 4; ++nt)
                    acc[s][nt] = __builtin_amdgcn_mfma_f32_16x16x32_bf16(af, bf[nt], acc[s][nt], 0, 0, 0);
            }
        }
    }
    __syncthreads();
    float rb = rsqrtf(1.f + 1e-5f);
    if (MODE == 0) {
        short* outS = inl_s;  // [128 pos][72 pad] bf16
#pragma unroll
        for (int nt = 0; nt < 4; ++nt) {
            int oc = nt * 16 + l15;
            float sc_ = bnw[oc] * rb, sh_ = bnb[oc];
#pragma unroll
            for (int s = 0; s < 2; ++s) {
                f32x4 v = acc[s][nt];
#pragma unroll
                for (int r = 0; r < 4; ++r) {
                    int pos = wv * 32 + s * 16 + quad * 4 + r;
                    float val = v[r] * sc_ + sh_;
                    val = val >= 0.f ? val : 0.01f * val;
                    outS[pos * 72 + oc] = f2b(val);
                }
            }
        }
        __syncthreads();
        for (int i = tid; i < 1024; i += 256) {
            int p = i >> 3, cq = i & 7;
            short8 v = *(const short8*)&outS[p * 72 + cq * 8];
            int y = p >> 5, x = p & 31;
            *(short8*)&goutS[((size_t)(bb * NTOK + z0 * 1024 + (y0 + y) * 32 + x)) * 64 + cq * 8] = v;
        }
    } else {
        float* outF = (float*)inl_s;  // [64 oc][132 pad] fp32
#pragma unroll
        for (int nt = 0; nt < 4; ++nt) {
            int oc = nt * 16 + l15;
#pragma unroll
            for (int s = 0; s < 2; ++s) {
                f32x4 v = acc[s][nt];
#pragma unroll
                for (int r = 0; r < 4; ++r) {
                    int pos = wv * 32 + s * 16 + quad * 4 + r;
                    outF[oc * 132 + pos] = v[r];
                }
            }
        }
        __syncthreads();
        for (int i = tid; i < 2048; i += 256) {
            int oc = i >> 5, xq = i & 31;
            int pos0 = xq * 4;
            f32x4 c4 = *(const f32x4*)&outF[oc * 132 + pos0];
            int y = pos0 >> 5, xx = pos0 & 31;
            size_t g = (((size_t)(bb * 64 + oc)) << 15) + ((z0 * 32 + (y0 + y)) * 32 + xx);
            f32x4 sk = *(const f32x4*)&skip[g];
            float sc_ = bnw[oc] * rb, sh_ = bnb[oc];
            f32x4 o;
#pragma unroll
            for (int r = 0; r < 4; ++r) {
                float val = c4[r] * sc_ + sh_ + sk[r];
                o[r] = val >= 0.f ? val : 0.01f * val;
            }
            *(f32x4*)&goutF[g] = o;
        }
    }
}

// ---------------- conv8 (1x1x1) + bias + final residual, in-place on d_out ----------------
__global__ __launch_bounds__(256) void k_conv8(
    const float* __restrict__ in2, const float* __restrict__ w8,
    const float* __restrict__ b8, float* __restrict__ io)
{
    __shared__ float wl[64][64];   // [ci][c]
    int tid = threadIdx.x;
    for (int i = tid; i < 4096; i += 256) {
        int c = i & 63, ci = i >> 6;
        wl[ci][c] = w8[c * 64 + ci];
    }
    __syncthreads();
    int bidx = blockIdx.x;
    int b = bidx >> 7;
    int n = ((bidx & 127) << 8) + tid;
    float acc[64];
#pragma unroll
    for (int c = 0; c < 64; ++c) acc[c] = 0.f;
    const float* ip = in2 + (((size_t)b) << 21) + n;
    for (int ci = 0; ci < 64; ++ci) {
        float v = ip[(size_t)ci << 15];
        const float4* wr = (const float4*)&wl[ci][0];
#pragma unroll
        for (int c4 = 0; c4 < 16; ++c4) {
            float4 wv = wr[c4];
            acc[c4 * 4 + 0] += v * wv.x; acc[c4 * 4 + 1] += v * wv.y;
            acc[c4 * 4 + 2] += v * wv.z; acc[c4 * 4 + 3] += v * wv.w;
        }
    }
    float* op = io + (((size_t)b) << 21) + n;
#pragma unroll
    for (int c = 0; c < 64; ++c) {
        size_t idx = (size_t)c << 15;
        op[idx] = op[idx] + b8[c] + acc[c];
    }
}

extern "C" void kernel_launch(void* const* d_in, const int* in_sizes, int n_in,
                              void* d_out, int out_size, void* d_ws, size_t ws_size,
                              hipStream_t stream) {
    const float* x      = (const float*)d_in[0];
    const float* ln_w   = (const float*)d_in[1];
    const float* ln_b   = (const float*)d_in[2];
    const float* gamma  = (const float*)d_in[3];
    const float* temp1  = (const float*)d_in[4];
    const float* temp2  = (const float*)d_in[5];
    const float* W_qkvv = (const float*)d_in[6];
    const float* W_EF   = (const float*)d_in[7];
    const float* b_EF   = (const float*)d_in[8];
    const float* W_o1   = (const float*)d_in[9];
    const float* b_o1   = (const float*)d_in[10];
    const float* W_o2   = (const float*)d_in[11];
    const float* b_o2   = (const float*)d_in[12];
    const float* conv1w = (const float*)d_in[13];
    const float* conv2w = (const float*)d_in[14];
    const float* bn1_w  = (const float*)d_in[15];
    const float* bn1_b  = (const float*)d_in[16];
    const float* bn2_w  = (const float*)d_in[17];
    const float* bn2_b  = (const float*)d_in[18];
    const float* conv8w = (const float*)d_in[19];
    const float* conv8b = (const float*)d_in[20];

    float* ws   = (float*)d_ws;
    float* qkvv = ws;                        // 16777216 floats
    float* buf1 = qkvv + 16777216;           // 4194304 (x_ca)
    float* buf2 = buf1 + 4194304;            // 4194304 (x_sa, then out2 fp32)
    float* kp   = buf2 + 4194304;            // 8192
    float* vp   = kp + 8192;                 // 8192
    float* qd   = vp + 8192;                 // 2048
    float* a_ca = qd + 2048;                 // 2048
    float* iqn  = a_ca + 2048;               // 128
    float* ikn  = iqn + 128;                 // 128
    short* gA   = (short*)(ikn + 128);       // 4194304 bf16 (attn_skip NHWC)
    short* g1   = gA + 4194304;              // 4194304 bf16 (out1 NHWC)
    short* wb1  = g1 + 4194304;              // 110592 bf16
    short* wb2  = wb1 + 110592;              // 110592 bf16

    float* attn_skip = (float*)d_out;

    hipLaunchKernelGGL(k_init, dim3(32), dim3(256), 0, stream, b_EF, kp, vp, qd);
    hipLaunchKernelGGL(k_repack, dim3(864), dim3(256), 0, stream,
                       conv1w, conv2w, wb1, wb2);
    hipLaunchKernelGGL(k_ln_qkvv, dim3(1024), dim3(256), 0, stream,
                       x, ln_w, ln_b, W_qkvv, qkvv);
    hipLaunchKernelGGL(k_norms, dim3(256), dim3(256), 0, stream, qkvv, iqn, ikn);
    hipLaunchKernelGGL(k_proj_kernel, dim3(64, 8), dim3(256), 0, stream,
                       qkvv, W_EF, kp, vp);
    hipLaunchKernelGGL(k_qdot, dim3(64, 8), dim3(256), 0, stream, qkvv, qd);
    hipLaunchKernelGGL(k_softmax_ca, dim3(1), dim3(128), 0, stream,
                       qd, iqn, ikn, temp1, a_ca);
    hipLaunchKernelGGL(k_xca, dim3(128, 8), dim3(256), 0, stream, qkvv, a_ca, buf1);
    hipLaunchKernelGGL(k_attn_sa, dim3(128, 8), dim3(256), 0, stream,
                       qkvv, iqn, kp, vp, temp2, buf2);
    hipLaunchKernelGGL(k_epilogue, dim3(1024), dim3(256), 0, stream,
                       x, buf2, buf1, W_o1, b_o1, W_o2, b_o2, gamma, attn_skip, gA);
    hipLaunchKernelGGL((k_conv3m<0>), dim3(512), dim3(256), 0, stream,
                       gA, wb1, bn1_w, bn1_b, (const float*)nullptr, g1, (float*)nullptr);
    hipLaunchKernelGGL((k_conv3m<1>), dim3(512), dim3(256), 0, stream,
                       g1, wb2, bn2_w, bn2_b, attn_skip, (short*)nullptr, buf2);
    hipLaunchKernelGGL(k_conv8, dim3(256), dim3(256), 0, stream,
                       buf2, conv8w, conv8b, attn_skip);
}

// Round 3
// 334.409 us; speedup vs baseline: 3.2222x; 1.3553x over previous
//
#include <hip/hip_runtime.h>

#define NTOK 32768

typedef __attribute__((ext_vector_type(8))) short short8;
typedef __attribute__((ext_vector_type(4))) short short4_t;
typedef __attribute__((ext_vector_type(4))) float f32x4;

__device__ __forceinline__ short f2b(float f) {
    union { float f; unsigned u; } v; v.f = f;
    unsigned r = v.u + 0x7fffu + ((v.u >> 16) & 1u);
    return (short)(r >> 16);
}

// ---------------- init small buffers ----------------
__global__ void k_init(const float* __restrict__ bEF, float* __restrict__ kp,
                       float* __restrict__ vp, float* __restrict__ qd)
{
    int i = blockIdx.x * 256 + threadIdx.x;
    if (i < 8192) { kp[i] = bEF[i & 63]; vp[i] = bEF[i & 63]; }
    if (i < 2048) qd[i] = 0.f;
}

// ------- repack conv weights [oc][ic][27] fp32 -> [tap][oc][ic] bf16; also w8 -> bf16 -------
__global__ void k_repack(const float* __restrict__ w1, const float* __restrict__ w2,
                         const float* __restrict__ w8, short* __restrict__ wb1,
                         short* __restrict__ wb2, short* __restrict__ wb8)
{
    int i = blockIdx.x * 256 + threadIdx.x;
    if (i >= 225280) return;
    if (i >= 221184) { int j = i - 221184; wb8[j] = f2b(w8[j]); return; }
    int sel = i >= 110592;
    int j = sel ? i - 110592 : i;
    int tap = j >> 12;
    int r = j & 4095;
    int oc = r >> 6, ic = r & 63;
    const float* w = sel ? w2 : w1;
    short* o = sel ? wb2 : wb1;
    o[j] = f2b(w[(oc * 64 + ic) * 27 + tap]);
}

// ---------------- fused LayerNorm + QKVV GEMM (MFMA) ----------------
// qkvv layout: [isel(4)][b(2)][h(4)][d(16)][N]
__global__ __launch_bounds__(256) void k_ln_qkvv(
    const float* __restrict__ x, const float* __restrict__ lnw,
    const float* __restrict__ lnb, const float* __restrict__ Wq,
    float* __restrict__ qkvv)
{
    __shared__ __align__(16) short Wl[256 * 72];        // 36864 B, bf16 [out][72]
    __shared__ __align__(16) float trans_s[2 * 64 * 68]; // 34816 B; aliases al early
    __shared__ float red1[4][64], red2[4][64];
    __shared__ float mu_s[64], rs_s[64];
    short* al = (short*)trans_s;                         // bf16 [64 t][72]

    int bid = blockIdx.x;
    int b = bid >> 9;
    int n0 = (bid & 511) << 6;
    int tid = threadIdx.x;

    // stage W as bf16 (rows 72-short padded, 16B-aligned fragment reads)
    for (int i = tid; i < 4096; i += 256) {
        int out = i >> 4, cb = (i & 15) * 4;
        f32x4 wv = *(const f32x4*)&Wq[out * 64 + cb];
        short4_t sv;
#pragma unroll
        for (int j = 0; j < 4; ++j) sv[j] = f2b(wv[j]);
        *(short4_t*)&Wl[out * 72 + cb] = sv;
    }

    // LayerNorm: thread (t, cq) owns 16 channels of token n0+t
    int t = tid & 63, cq = tid >> 6;
    float xr[16];
    float s1 = 0.f, s2 = 0.f;
    const float* xb = x + (((size_t)(b * 64 + cq * 16)) << 15) + n0 + t;
#pragma unroll
    for (int j = 0; j < 16; ++j) {
        float v = xb[(size_t)j << 15];
        xr[j] = v; s1 += v; s2 += v * v;
    }
    red1[cq][t] = s1; red2[cq][t] = s2;
    __syncthreads();
    if (tid < 64) {
        float a = red1[0][tid] + red1[1][tid] + red1[2][tid] + red1[3][tid];
        float q = red2[0][tid] + red2[1][tid] + red2[2][tid] + red2[3][tid];
        float mu = a * (1.f / 64.f);
        float var = q * (1.f / 64.f) - mu * mu;
        mu_s[tid] = mu;
        rs_s[tid] = rsqrtf(var + 1e-5f);
    }
    __syncthreads();
    {
        float mu = mu_s[t], rs = rs_s[t];
        short8 p0, p1;
#pragma unroll
        for (int j = 0; j < 8; ++j) {
            int c = cq * 16 + j;
            p0[j] = f2b((xr[j] - mu) * rs * lnw[c] + lnb[c]);
        }
#pragma unroll
        for (int j = 0; j < 8; ++j) {
            int c = cq * 16 + 8 + j;
            p1[j] = f2b((xr[8 + j] - mu) * rs * lnw[c] + lnb[c]);
        }
        *(short8*)&al[t * 72 + cq * 16] = p0;
        *(short8*)&al[t * 72 + cq * 16 + 8] = p1;
    }
    __syncthreads();

    // MFMA: wave w owns 64 outputs, all 64 tokens
    int w = tid >> 6, lane = tid & 63, l15 = lane & 15, quad = lane >> 4;
    f32x4 acc[4][4];
#pragma unroll
    for (int mt = 0; mt < 4; ++mt)
#pragma unroll
        for (int nt = 0; nt < 4; ++nt) acc[mt][nt] = (f32x4){0.f, 0.f, 0.f, 0.f};
#pragma unroll
    for (int ks = 0; ks < 2; ++ks) {
        short8 af[4], bf[4];
#pragma unroll
        for (int mt = 0; mt < 4; ++mt)
            af[mt] = *(const short8*)&al[(mt * 16 + l15) * 72 + quad * 8 + ks * 32];
#pragma unroll
        for (int nt = 0; nt < 4; ++nt)
            bf[nt] = *(const short8*)&Wl[(w * 64 + nt * 16 + l15) * 72 + quad * 8 + ks * 32];
#pragma unroll
        for (int mt = 0; mt < 4; ++mt)
#pragma unroll
            for (int nt = 0; nt < 4; ++nt)
                acc[mt][nt] = __builtin_amdgcn_mfma_f32_16x16x32_bf16(af[mt], bf[nt], acc[mt][nt], 0, 0, 0);
    }

    // write out via LDS transpose (coalesced per-plane stores), 2 passes
    for (int p = 0; p < 2; ++p) {
        __syncthreads();
        if ((w >> 1) == p) {
            float* tr = trans_s + (w & 1) * (64 * 68);
#pragma unroll
            for (int mt = 0; mt < 4; ++mt)
#pragma unroll
                for (int nt = 0; nt < 4; ++nt)
                    *(f32x4*)&tr[(nt * 16 + l15) * 68 + mt * 16 + quad * 4] = acc[mt][nt];
        }
        __syncthreads();
        for (int i = tid; i < 2048; i += 256) {
            int ol = i >> 4, tq = (i & 15) * 4;
            f32x4 v = *(const f32x4*)&trans_s[(ol >> 6) * (64 * 68) + (ol & 63) * 68 + tq];
            int o = p * 128 + ol;
            int isel = o >> 6, h = (o >> 4) & 3, d = o & 15;
            *(f32x4*)&qkvv[(size_t)(((isel * 2 + b) * 4 + h) * 16 + d) * NTOK + n0 + tq] = v;
        }
    }
}

// ---------------- L2 norms of q,k over N ----------------
__global__ __launch_bounds__(256) void k_norms(const float* __restrict__ qkvv,
    float* __restrict__ inv_qn, float* __restrict__ inv_kn)
{
    __shared__ float red[256];
    int r = blockIdx.x;
    int arr = r >> 7;
    int sub = r & 127;
    const float4* p = (const float4*)(qkvv + (size_t)(arr * 128 + sub) * NTOK);
    float s = 0.f;
    int tid = threadIdx.x;
    for (int i = tid; i < NTOK / 4; i += 256) {
        float4 v = p[i];
        s += v.x * v.x + v.y * v.y + v.z * v.z + v.w * v.w;
    }
    red[tid] = s; __syncthreads();
    for (int off = 128; off > 0; off >>= 1) {
        if (tid < off) red[tid] += red[tid + off];
        __syncthreads();
    }
    if (tid == 0) {
        float inv = 1.f / fmaxf(sqrtf(red[0]), 1e-12f);
        (arr == 0 ? inv_qn : inv_kn)[sub] = inv;
    }
}

// ---------------- k_proj / v_proj ----------------
__global__ __launch_bounds__(256) void k_proj_kernel(
    const float* __restrict__ qkvv, const float* __restrict__ WEF,
    float* __restrict__ kp, float* __restrict__ vp)
{
    __shared__ float Wl[64][132];
    __shared__ float kl[16][132];
    __shared__ float vl[16][132];
    int kc = blockIdx.x;
    int bh = blockIdx.y;
    int b = bh >> 2, h = bh & 3;
    int tid = threadIdx.x;
    int d_ = tid & 15, pg = tid >> 4;
    float ak[4] = {0, 0, 0, 0}, av[4] = {0, 0, 0, 0};
    const float* kbase = qkvv + (size_t)(((2 + b) * 4 + h) * 16) * NTOK;
    const float* vbase = qkvv + (size_t)(((6 + b) * 4 + h) * 16) * NTOK;
    for (int sub = 0; sub < 4; ++sub) {
        int nb = kc * 512 + sub * 128;
        __syncthreads();
        for (int i = tid; i < 64 * 128; i += 256) {
            int pp = i >> 7, nn = i & 127;
            Wl[pp][nn] = WEF[(size_t)pp * NTOK + nb + nn];
        }
        for (int i = tid; i < 16 * 128; i += 256) {
            int dd = i >> 7, nn = i & 127;
            kl[dd][nn] = kbase[(size_t)dd * NTOK + nb + nn];
            vl[dd][nn] = vbase[(size_t)dd * NTOK + nb + nn];
        }
        __syncthreads();
        for (int n4 = 0; n4 < 32; ++n4) {
            float4 kv = *(const float4*)&kl[d_][n4 * 4];
            float4 vv = *(const float4*)&vl[d_][n4 * 4];
#pragma unroll
            for (int j = 0; j < 4; ++j) {
                float4 wv = *(const float4*)&Wl[pg + j * 16][n4 * 4];
                ak[j] += kv.x * wv.x + kv.y * wv.y + kv.z * wv.z + kv.w * wv.w;
                av[j] += vv.x * wv.x + vv.y * wv.y + vv.z * wv.z + vv.w * wv.w;
            }
        }
    }
    int outbase = ((b * 4 + h) * 16 + d_) * 64;
#pragma unroll
    for (int j = 0; j < 4; ++j) {
        atomicAdd(&kp[outbase + pg + j * 16], ak[j]);
        atomicAdd(&vp[outbase + pg + j * 16], av[j]);
    }
}

// ---------------- channel-attention logits ----------------
__global__ __launch_bounds__(256) void k_qdot(
    const float* __restrict__ qkvv, float* __restrict__ qd)
{
    __shared__ float ql[16][132];
    __shared__ float kl[16][132];
    int kc = blockIdx.x; int bh = blockIdx.y;
    int b = bh >> 2, h = bh & 3;
    int tid = threadIdx.x;
    int d_ = tid >> 4, e_ = tid & 15;
    float acc = 0.f;
    const float* qbase = qkvv + (size_t)((b * 4 + h) * 16) * NTOK;
    const float* kbase = qkvv + (size_t)(((2 + b) * 4 + h) * 16) * NTOK;
    for (int sub = 0; sub < 4; ++sub) {
        int nb = kc * 512 + sub * 128;
        __syncthreads();
        for (int i = tid; i < 16 * 128; i += 256) {
            int dd = i >> 7, nn = i & 127;
            ql[dd][nn] = qbase[(size_t)dd * NTOK + nb + nn];
            kl[dd][nn] = kbase[(size_t)dd * NTOK + nb + nn];
        }
        __syncthreads();
        for (int n4 = 0; n4 < 32; ++n4) {
            float4 qv = *(const float4*)&ql[d_][n4 * 4];
            float4 kv = *(const float4*)&kl[e_][n4 * 4];
            acc += qv.x * kv.x + qv.y * kv.y + qv.z * kv.z + qv.w * kv.w;
        }
    }
    atomicAdd(&qd[(bh * 16 + d_) * 16 + e_], acc);
}

// ---------------- channel-attention softmax ----------------
__global__ void k_softmax_ca(const float* __restrict__ qd,
    const float* __restrict__ inv_qn, const float* __restrict__ inv_kn,
    const float* __restrict__ temp1, float* __restrict__ attn)
{
    int r = threadIdx.x;
    if (r >= 128) return;
    int bh = r >> 4;
    int h = bh & 3;
    float iq = inv_qn[r];
    float t1 = temp1[h];
    float sc[16];
    float mx = -1e30f;
#pragma unroll
    for (int e = 0; e < 16; ++e) {
        float v = qd[r * 16 + e] * iq * inv_kn[bh * 16 + e] * t1;
        sc[e] = v; mx = fmaxf(mx, v);
    }
    float s = 0.f;
#pragma unroll
    for (int e = 0; e < 16; ++e) { sc[e] = __expf(sc[e] - mx); s += sc[e]; }
    float inv = 1.f / s;
#pragma unroll
    for (int e = 0; e < 16; ++e) attn[r * 16 + e] = sc[e] * inv;
}

// ---------------- x_ca ----------------
__global__ __launch_bounds__(256) void k_xca(
    const float* __restrict__ qkvv, const float* __restrict__ attn,
    float* __restrict__ xca)
{
    __shared__ float al[16][16];
    int bh = blockIdx.y; int b = bh >> 2, h = bh & 3;
    int tid = threadIdx.x;
    al[tid >> 4][tid & 15] = attn[bh * 256 + tid];
    __syncthreads();
    int n = blockIdx.x * 256 + tid;
    const float* vbase = qkvv + (size_t)(((4 + b) * 4 + h) * 16) * NTOK + n;
    float acc[16];
#pragma unroll
    for (int d = 0; d < 16; ++d) acc[d] = 0.f;
#pragma unroll
    for (int e = 0; e < 16; ++e) {
        float va = vbase[(size_t)e * NTOK];
#pragma unroll
        for (int d = 0; d < 16; ++d) acc[d] += al[d][e] * va;
    }
    float* op = xca + ((size_t)(b * NTOK + n)) * 64 + h * 16;
#pragma unroll
    for (int d4 = 0; d4 < 4; ++d4) {
        float4 v; v.x = acc[d4 * 4]; v.y = acc[d4 * 4 + 1];
        v.z = acc[d4 * 4 + 2]; v.w = acc[d4 * 4 + 3];
        *(float4*)&op[d4 * 4] = v;
    }
}

// ---------------- fused spatial attention ----------------
__global__ __launch_bounds__(256) void k_attn_sa(
    const float* __restrict__ qkvv, const float* __restrict__ inv_qn,
    const float* __restrict__ kp, const float* __restrict__ vp,
    const float* __restrict__ temp2, float* __restrict__ xsa)
{
    __shared__ float kl[16][64];
    __shared__ float vl[16][64];
    __shared__ float iq[16];
    int bh = blockIdx.y; int b = bh >> 2, h = bh & 3;
    int tid = threadIdx.x;
    for (int i = tid; i < 1024; i += 256) {
        kl[i >> 6][i & 63] = kp[bh * 1024 + i];
        vl[i >> 6][i & 63] = vp[bh * 1024 + i];
    }
    if (tid < 16) iq[tid] = inv_qn[bh * 16 + tid];
    __syncthreads();
    int n = blockIdx.x * 256 + tid;
    const float* qbase = qkvv + (size_t)(bh * 16) * NTOK + n;
    float qn_[16];
#pragma unroll
    for (int d = 0; d < 16; ++d) qn_[d] = qbase[(size_t)d * NTOK] * iq[d];
    float t2 = temp2[h];
    float sc[64];
#pragma unroll
    for (int p = 0; p < 64; ++p) sc[p] = 0.f;
#pragma unroll
    for (int d = 0; d < 16; ++d) {
        float qv = qn_[d];
        const float4* kr = (const float4*)&kl[d][0];
#pragma unroll
        for (int p4 = 0; p4 < 16; ++p4) {
            float4 kv = kr[p4];
            sc[p4 * 4 + 0] += qv * kv.x; sc[p4 * 4 + 1] += qv * kv.y;
            sc[p4 * 4 + 2] += qv * kv.z; sc[p4 * 4 + 3] += qv * kv.w;
        }
    }
    float mx = -1e30f;
#pragma unroll
    for (int p = 0; p < 64; ++p) { sc[p] *= t2; mx = fmaxf(mx, sc[p]); }
    float s = 0.f;
#pragma unroll
    for (int p = 0; p < 64; ++p) { sc[p] = __expf(sc[p] - mx); s += sc[p]; }
    float inv = 1.f / s;
#pragma unroll
    for (int p = 0; p < 64; ++p) sc[p] *= inv;
    float* ob = xsa + (size_t)b * 2097152 + n;
#pragma unroll
    for (int d = 0; d < 16; ++d) {
        const float4* vr = (const float4*)&vl[d][0];
        float a0 = 0, a1 = 0, a2 = 0, a3 = 0;
#pragma unroll
        for (int p4 = 0; p4 < 16; ++p4) {
            float4 vv = vr[p4];
            a0 += sc[p4 * 4] * vv.x; a1 += sc[p4 * 4 + 1] * vv.y;
            a2 += sc[p4 * 4 + 2] * vv.z; a3 += sc[p4 * 4 + 3] * vv.w;
        }
        ob[(size_t)(d * 4 + h) * NTOK] = (a0 + a1) + (a2 + a3);
    }
}

// ---------------- EPA epilogue: proj + gamma + residual -> attn_skip (fp32 NCHW) + gA (bf16 NHWC)
__global__ __launch_bounds__(256) void k_epilogue(
    const float* __restrict__ x, const float* __restrict__ xsa,
    const float* __restrict__ xca, const float* __restrict__ Wo1,
    const float* __restrict__ bo1, const float* __restrict__ Wo2,
    const float* __restrict__ bo2, const float* __restrict__ gamma,
    float* __restrict__ attn_skip, short* __restrict__ gA)
{
    __shared__ float W1[32][64];
    __shared__ float W2[32][64];
    int tid = threadIdx.x;
    for (int i = tid; i < 2048; i += 256) {
        W1[i >> 6][i & 63] = Wo1[i];
        W2[i >> 6][i & 63] = Wo2[i];
    }
    __syncthreads();
    int bid = blockIdx.x;
    int b = bid >> 9;
    int n0 = (bid & 511) << 6;
    int t = tid & 63, cg = tid >> 6;
    int n = n0 + t;
    const float* row = (cg < 2) ? xsa + (size_t)b * 2097152 + (size_t)n * 64
                                : xca + ((size_t)(b * NTOK + n)) * 64;
    const float* Wb = (cg < 2) ? &W1[(cg & 1) * 16][0] : &W2[(cg & 1) * 16][0];
    const float* bias = (cg < 2) ? bo1 + (cg & 1) * 16 : bo2 + (cg & 1) * 16;
    float acc[16];
#pragma unroll
    for (int j = 0; j < 16; ++j) acc[j] = 0.f;
    const float4* r4 = (const float4*)row;
#pragma unroll
    for (int c4 = 0; c4 < 16; ++c4) {
        float4 rv = r4[c4];
#pragma unroll
        for (int j = 0; j < 16; ++j) {
            float4 wv = *(const float4*)&Wb[j * 64 + c4 * 4];
            acc[j] += rv.x * wv.x + rv.y * wv.y + rv.z * wv.z + rv.w * wv.w;
        }
    }
    float vals[16];
#pragma unroll
    for (int j = 0; j < 16; ++j) {
        int c = cg * 16 + j;
        size_t idx = (((size_t)(b * 64 + c)) << 15) + n;
        float v = x[idx] + gamma[c] * (acc[j] + bias[j]);
        attn_skip[idx] = v;
        vals[j] = v;
    }
    short8 lo, hi;
#pragma unroll
    for (int j = 0; j < 8; ++j) { lo[j] = f2b(vals[j]); hi[j] = f2b(vals[j + 8]); }
    short* gp = gA + ((size_t)(b * NTOK + n)) * 64 + cg * 16;
    *(short8*)&gp[0] = lo;
    *(short8*)&gp[8] = hi;
}

// ---------------- MFMA implicit-GEMM 3x3x3 conv ----------------
// Input: NHWC bf16 gin[b][zyx][64ic]. Weights: wb[tap][oc][ic] bf16.
// MODE 0: out = lrelu(bn1(conv))                     -> goutS NHWC bf16
// MODE 1: out2 = lrelu(bn2(conv)+skip); then fused 1x1x1 conv8:
//         io = skip + conv8(out2) + b8  (fp32 NCHW rmw of d_out)
template <int MODE>
__global__ __launch_bounds__(256) void k_conv3m(
    const short* __restrict__ gin, const short* __restrict__ wb,
    const float* __restrict__ bnw, const float* __restrict__ bnb,
    const float* __restrict__ skip, short* __restrict__ goutS,
    const short* __restrict__ wb8, const float* __restrict__ b8,
    float* __restrict__ io)
{
    __shared__ __align__(16) short inl_s[24480];   // [3z][6y][34x][40 icpad]
    __shared__ __align__(16) short wl_s[5120];     // 2x [64 oc][40 icpad]; later w8 [64][80]
    __shared__ __align__(16) short a2_s[MODE ? 9216 : 16];  // bf16 [128 pos][72] (MODE 1)
    int bx = blockIdx.x;
    int bb = bx >> 8;
    int z0 = (bx >> 3) & 31;
    int y0 = (bx & 7) * 4;
    int tid = threadIdx.x;
    int lane = tid & 63, wv = tid >> 6;
    int l15 = lane & 15, quad = lane >> 4;
    int wo = tid >> 2, wq = tid & 3;

    f32x4 acc[2][4];
#pragma unroll
    for (int s = 0; s < 2; ++s)
#pragma unroll
        for (int nt = 0; nt < 4; ++nt) acc[s][nt] = (f32x4){0.f, 0.f, 0.f, 0.f};

    int boff[4];
#pragma unroll
    for (int nt = 0; nt < 4; ++nt) boff[nt] = (nt * 16 + l15) * 40 + quad * 8;

    for (int chunk = 0; chunk < 2; ++chunk) {
        __syncthreads();
        for (int i = tid; i < 2448; i += 256) {
            int p = i >> 2, icq = i & 3;
            int xi = p % 34; int t2 = p / 34; int yi = t2 % 6; int zi = t2 / 6;
            int gz = z0 + zi - 1, gy = y0 + yi - 1, gx = xi - 1;
            short8 v = {0, 0, 0, 0, 0, 0, 0, 0};
            if ((unsigned)gz < 32u && (unsigned)gy < 32u && (unsigned)gx < 32u)
                v = *(const short8*)&gin[((size_t)(bb * NTOK + gz * 1024 + gy * 32 + gx)) * 64 + chunk * 32 + icq * 8];
            *(short8*)&inl_s[p * 40 + icq * 8] = v;
        }
        short8 wreg = *(const short8*)&wb[(size_t)wo * 64 + chunk * 32 + wq * 8];
        for (int tap = 0; tap < 27; ++tap) {
            *(short8*)&wl_s[(tap & 1) * 2560 + wo * 40 + wq * 8] = wreg;
            if (tap < 26)
                wreg = *(const short8*)&wb[(size_t)((tap + 1) * 64 + wo) * 64 + chunk * 32 + wq * 8];
            __syncthreads();
            int kz = tap / 9, ky = (tap / 3) % 3, kx = tap % 3;
            const short* wlb = &wl_s[(tap & 1) * 2560];
            short8 bf[4];
#pragma unroll
            for (int nt = 0; nt < 4; ++nt) bf[nt] = *(const short8*)&wlb[boff[nt]];
            int rowb = (kz * 6 + wv + ky) * 34;
#pragma unroll
            for (int s = 0; s < 2; ++s) {
                short8 af = *(const short8*)&inl_s[(rowb + s * 16 + l15 + kx) * 40 + quad * 8];
#pragma unroll
                for (int nt = 0; nt < 4; ++nt)
                    acc[s][nt] = __builtin_amdgcn_mfma_f32_16x16x32_bf16(af, bf[nt], acc[s][nt], 0, 0, 0);
            }
        }
    }
    __syncthreads();
    float rb = rsqrtf(1.f + 1e-5f);
    if (MODE == 0) {
        short* outS = inl_s;  // [128 pos][72 pad] bf16
#pragma unroll
        for (int nt = 0; nt < 4; ++nt) {
            int oc = nt * 16 + l15;
            float sc_ = bnw[oc] * rb, sh_ = bnb[oc];
#pragma unroll
            for (int s = 0; s < 2; ++s) {
                f32x4 v = acc[s][nt];
#pragma unroll
                for (int r = 0; r < 4; ++r) {
                    int pos = wv * 32 + s * 16 + quad * 4 + r;
                    float val = v[r] * sc_ + sh_;
                    val = val >= 0.f ? val : 0.01f * val;
                    outS[pos * 72 + oc] = f2b(val);
                }
            }
        }
        __syncthreads();
        for (int i = tid; i < 1024; i += 256) {
            int p = i >> 3, cq = i & 7;
            short8 v = *(const short8*)&outS[p * 72 + cq * 8];
            int y = p >> 5, x = p & 31;
            *(short8*)&goutS[((size_t)(bb * NTOK + z0 * 1024 + (y0 + y) * 32 + x)) * 64 + cq * 8] = v;
        }
    } else {
        float* outF = (float*)inl_s;  // [64 oc][132 pad pos] fp32
#pragma unroll
        for (int nt = 0; nt < 4; ++nt) {
            int oc = nt * 16 + l15;
#pragma unroll
            for (int s = 0; s < 2; ++s) {
                f32x4 v = acc[s][nt];
#pragma unroll
                for (int r = 0; r < 4; ++r) {
                    int pos = wv * 32 + s * 16 + quad * 4 + r;
                    outF[oc * 132 + pos] = v[r];
                }
            }
        }
        __syncthreads();
        // pass A: out2 = lrelu(bn2+skip) -> bf16 A-tile; keep skip in regs
        f32x4 skr[8];
#pragma unroll
        for (int it = 0; it < 8; ++it) {
            int i = it * 256 + tid;
            int oc = i >> 5, xq = i & 31, pos0 = xq * 4;
            f32x4 c4 = *(const f32x4*)&outF[oc * 132 + pos0];
            int y = pos0 >> 5, xx = pos0 & 31;
            size_t g = (((size_t)(bb * 64 + oc)) << 15) + ((z0 * 32 + (y0 + y)) * 32 + xx);
            f32x4 sk = *(const f32x4*)&skip[g];
            skr[it] = sk;
            float sc_ = bnw[oc] * rb, sh_ = bnb[oc];
#pragma unroll
            for (int r = 0; r < 4; ++r) {
                float val = c4[r] * sc_ + sh_ + sk[r];
                val = val >= 0.f ? val : 0.01f * val;
                a2_s[(pos0 + r) * 72 + oc] = f2b(val);
            }
        }
        // stage w8 bf16 [64 out][80 pad]
        for (int i = tid; i < 512; i += 256) {
            int ocw = i >> 3, cq = i & 7;
            *(short8*)&wl_s[ocw * 80 + cq * 8] = *(const short8*)&wb8[ocw * 64 + cq * 8];
        }
        __syncthreads();
        // MFMA pass 2: conv8 (1x1x1) on out2 tile
        f32x4 acc2[2][4];
#pragma unroll
        for (int s = 0; s < 2; ++s)
#pragma unroll
            for (int nt = 0; nt < 4; ++nt) acc2[s][nt] = (f32x4){0.f, 0.f, 0.f, 0.f};
#pragma unroll
        for (int ks = 0; ks < 2; ++ks) {
            short8 a8[2], b8f[4];
#pragma unroll
            for (int s = 0; s < 2; ++s)
                a8[s] = *(const short8*)&a2_s[(wv * 32 + s * 16 + l15) * 72 + quad * 8 + ks * 32];
#pragma unroll
            for (int nt = 0; nt < 4; ++nt)
                b8f[nt] = *(const short8*)&wl_s[(nt * 16 + l15) * 80 + quad * 8 + ks * 32];
#pragma unroll
            for (int s = 0; s < 2; ++s)
#pragma unroll
                for (int nt = 0; nt < 4; ++nt)
                    acc2[s][nt] = __builtin_amdgcn_mfma_f32_16x16x32_bf16(a8[s], b8f[nt], acc2[s][nt], 0, 0, 0);
        }
        __syncthreads();
        // transpose conv8 result -> outF [64 out][132 pos]
#pragma unroll
        for (int nt = 0; nt < 4; ++nt) {
            int oc = nt * 16 + l15;
#pragma unroll
            for (int s = 0; s < 2; ++s) {
                f32x4 v = acc2[s][nt];
#pragma unroll
                for (int r = 0; r < 4; ++r) {
                    int pos = wv * 32 + s * 16 + quad * 4 + r;
                    outF[oc * 132 + pos] = v[r];
                }
            }
        }
        __syncthreads();
        // final: io = attn_skip + conv8 + b8  (attn_skip values held in skr)
#pragma unroll
        for (int it = 0; it < 8; ++it) {
            int i = it * 256 + tid;
            int oc = i >> 5, xq = i & 31, pos0 = xq * 4;
            f32x4 cv = *(const f32x4*)&outF[oc * 132 + pos0];
            int y = pos0 >> 5, xx = pos0 & 31;
            size_t g = (((size_t)(bb * 64 + oc)) << 15) + ((z0 * 32 + (y0 + y)) * 32 + xx);
            float bias8 = b8[oc];
            f32x4 o;
#pragma unroll
            for (int r = 0; r < 4; ++r) o[r] = skr[it][r] + cv[r] + bias8;
            *(f32x4*)&io[g] = o;
        }
    }
}

extern "C" void kernel_launch(void* const* d_in, const int* in_sizes, int n_in,
                              void* d_out, int out_size, void* d_ws, size_t ws_size,
                              hipStream_t stream) {
    const float* x      = (const float*)d_in[0];
    const float* ln_w   = (const float*)d_in[1];
    const float* ln_b   = (const float*)d_in[2];
    const float* gamma  = (const float*)d_in[3];
    const float* temp1  = (const float*)d_in[4];
    const float* temp2  = (const float*)d_in[5];
    const float* W_qkvv = (const float*)d_in[6];
    const float* W_EF   = (const float*)d_in[7];
    const float* b_EF   = (const float*)d_in[8];
    const float* W_o1   = (const float*)d_in[9];
    const float* b_o1   = (const float*)d_in[10];
    const float* W_o2   = (const float*)d_in[11];
    const float* b_o2   = (const float*)d_in[12];
    const float* conv1w = (const float*)d_in[13];
    const float* conv2w = (const float*)d_in[14];
    const float* bn1_w  = (const float*)d_in[15];
    const float* bn1_b  = (const float*)d_in[16];
    const float* bn2_w  = (const float*)d_in[17];
    const float* bn2_b  = (const float*)d_in[18];
    const float* conv8w = (const float*)d_in[19];
    const float* conv8b = (const float*)d_in[20];

    float* ws   = (float*)d_ws;
    float* qkvv = ws;                        // 16777216 floats
    float* buf1 = qkvv + 16777216;           // 4194304 (x_ca)
    float* buf2 = buf1 + 4194304;            // 4194304 (x_sa)
    float* kp   = buf2 + 4194304;            // 8192
    float* vp   = kp + 8192;                 // 8192
    float* qd   = vp + 8192;                 // 2048
    float* a_ca = qd + 2048;                 // 2048
    float* iqn  = a_ca + 2048;               // 128
    float* ikn  = iqn + 128;                 // 128
    short* gA   = (short*)(ikn + 128);       // 4194304 bf16 (attn_skip NHWC)
    short* g1   = gA + 4194304;              // 4194304 bf16 (out1 NHWC)
    short* wb1  = g1 + 4194304;              // 110592 bf16
    short* wb2  = wb1 + 110592;              // 110592 bf16
    short* wb8  = wb2 + 110592;              // 4096 bf16

    float* attn_skip = (float*)d_out;

    hipLaunchKernelGGL(k_init, dim3(32), dim3(256), 0, stream, b_EF, kp, vp, qd);
    hipLaunchKernelGGL(k_repack, dim3(880), dim3(256), 0, stream,
                       conv1w, conv2w, conv8w, wb1, wb2, wb8);
    hipLaunchKernelGGL(k_ln_qkvv, dim3(1024), dim3(256), 0, stream,
                       x, ln_w, ln_b, W_qkvv, qkvv);
    hipLaunchKernelGGL(k_norms, dim3(256), dim3(256), 0, stream, qkvv, iqn, ikn);
    hipLaunchKernelGGL(k_proj_kernel, dim3(64, 8), dim3(256), 0, stream,
                       qkvv, W_EF, kp, vp);
    hipLaunchKernelGGL(k_qdot, dim3(64, 8), dim3(256), 0, stream, qkvv, qd);
    hipLaunchKernelGGL(k_softmax_ca, dim3(1), dim3(128), 0, stream,
                       qd, iqn, ikn, temp1, a_ca);
    hipLaunchKernelGGL(k_xca, dim3(128, 8), dim3(256), 0, stream, qkvv, a_ca, buf1);
    hipLaunchKernelGGL(k_attn_sa, dim3(128, 8), dim3(256), 0, stream,
                       qkvv, iqn, kp, vp, temp2, buf2);
    hipLaunchKernelGGL(k_epilogue, dim3(1024), dim3(256), 0, stream,
                       x, buf2, buf1, W_o1, b_o1, W_o2, b_o2, gamma, attn_skip, gA);
    hipLaunchKernelGGL((k_conv3m<0>), dim3(512), dim3(256), 0, stream,
                       gA, wb1, bn1_w, bn1_b, (const float*)nullptr, g1,
                       (const short*)nullptr, (const float*)nullptr, (float*)nullptr);
    hipLaunchKernelGGL((k_conv3m<1>), dim3(512), dim3(256), 0, stream,
                       g1, wb2, bn2_w, bn2_b, attn_skip, (short*)nullptr,
                       wb8, conv8b, attn_skip);
}

// Round 4
// 264.238 us; speedup vs baseline: 4.0779x; 1.2656x over previous
//
#include <hip/hip_runtime.h>

#define NTOK 32768

typedef __attribute__((ext_vector_type(8))) short short8;
typedef __attribute__((ext_vector_type(4))) short short4_t;
typedef __attribute__((ext_vector_type(4))) float f32x4;

__device__ __forceinline__ short f2b(float f) {
    union { float f; unsigned u; } v; v.f = f;
    unsigned r = v.u + 0x7fffu + ((v.u >> 16) & 1u);
    return (short)(r >> 16);
}
__device__ __forceinline__ float b2f(short s) {
    union { float f; unsigned u; } v;
    v.u = ((unsigned)(unsigned short)s) << 16;
    return v.f;
}

// ---------------- init small buffers ----------------
__global__ void k_init(const float* __restrict__ bEF, float* __restrict__ kp,
                       float* __restrict__ vp, float* __restrict__ qd)
{
    int i = blockIdx.x * 256 + threadIdx.x;
    if (i < 8192) { kp[i] = bEF[i & 63]; vp[i] = bEF[i & 63]; }
    if (i < 2304) qd[i] = 0.f;   // qd(2048) + qn_acc(128) + kn_acc(128)
}

// ------- repack conv weights -> [tap][oc][ic] bf16; w8 -> bf16; W_EF -> bf16 -------
__global__ void k_repack(const float* __restrict__ w1, const float* __restrict__ w2,
                         const float* __restrict__ w8, const float* __restrict__ wef,
                         short* __restrict__ wb1, short* __restrict__ wb2,
                         short* __restrict__ wb8, short* __restrict__ wefb)
{
    int i = blockIdx.x * 256 + threadIdx.x;
    if (i >= 2322432) return;
    if (i >= 225280) { int j = i - 225280; wefb[j] = f2b(wef[j]); return; }
    if (i >= 221184) { int j = i - 221184; wb8[j] = f2b(w8[j]); return; }
    int sel = i >= 110592;
    int j = sel ? i - 110592 : i;
    int tap = j >> 12;
    int r = j & 4095;
    int oc = r >> 6, ic = r & 63;
    const float* w = sel ? w2 : w1;
    short* o = sel ? wb2 : wb1;
    o[j] = f2b(w[(oc * 64 + ic) * 27 + tap]);
}

// ---------------- fused LayerNorm + QKVV GEMM (MFMA), bf16 output ----------------
// qkvvb layout: bf16 [isel(4)][b(2)][h(4)][d(16)][N]
__global__ __launch_bounds__(256) void k_ln_qkvv(
    const float* __restrict__ x, const float* __restrict__ lnw,
    const float* __restrict__ lnb, const float* __restrict__ Wq,
    short* __restrict__ qkvvb)
{
    __shared__ __align__(16) short Wl[256 * 72];
    __shared__ __align__(16) float trans_s[2 * 64 * 68];
    __shared__ float red1[4][64], red2[4][64];
    __shared__ float mu_s[64], rs_s[64];
    short* al = (short*)trans_s;

    int bid = blockIdx.x;
    int b = bid >> 9;
    int n0 = (bid & 511) << 6;
    int tid = threadIdx.x;

    for (int i = tid; i < 4096; i += 256) {
        int out = i >> 4, cb = (i & 15) * 4;
        f32x4 wv = *(const f32x4*)&Wq[out * 64 + cb];
        short4_t sv;
#pragma unroll
        for (int j = 0; j < 4; ++j) sv[j] = f2b(wv[j]);
        *(short4_t*)&Wl[out * 72 + cb] = sv;
    }

    int t = tid & 63, cq = tid >> 6;
    float xr[16];
    float s1 = 0.f, s2 = 0.f;
    const float* xb = x + (((size_t)(b * 64 + cq * 16)) << 15) + n0 + t;
#pragma unroll
    for (int j = 0; j < 16; ++j) {
        float v = xb[(size_t)j << 15];
        xr[j] = v; s1 += v; s2 += v * v;
    }
    red1[cq][t] = s1; red2[cq][t] = s2;
    __syncthreads();
    if (tid < 64) {
        float a = red1[0][tid] + red1[1][tid] + red1[2][tid] + red1[3][tid];
        float q = red2[0][tid] + red2[1][tid] + red2[2][tid] + red2[3][tid];
        float mu = a * (1.f / 64.f);
        float var = q * (1.f / 64.f) - mu * mu;
        mu_s[tid] = mu;
        rs_s[tid] = rsqrtf(var + 1e-5f);
    }
    __syncthreads();
    {
        float mu = mu_s[t], rs = rs_s[t];
        short8 p0, p1;
#pragma unroll
        for (int j = 0; j < 8; ++j) {
            int c = cq * 16 + j;
            p0[j] = f2b((xr[j] - mu) * rs * lnw[c] + lnb[c]);
        }
#pragma unroll
        for (int j = 0; j < 8; ++j) {
            int c = cq * 16 + 8 + j;
            p1[j] = f2b((xr[8 + j] - mu) * rs * lnw[c] + lnb[c]);
        }
        *(short8*)&al[t * 72 + cq * 16] = p0;
        *(short8*)&al[t * 72 + cq * 16 + 8] = p1;
    }
    __syncthreads();

    int w = tid >> 6, lane = tid & 63, l15 = lane & 15, quad = lane >> 4;
    f32x4 acc[4][4];
#pragma unroll
    for (int mt = 0; mt < 4; ++mt)
#pragma unroll
        for (int nt = 0; nt < 4; ++nt) acc[mt][nt] = (f32x4){0.f, 0.f, 0.f, 0.f};
#pragma unroll
    for (int ks = 0; ks < 2; ++ks) {
        short8 af[4], bf[4];
#pragma unroll
        for (int mt = 0; mt < 4; ++mt)
            af[mt] = *(const short8*)&al[(mt * 16 + l15) * 72 + quad * 8 + ks * 32];
#pragma unroll
        for (int nt = 0; nt < 4; ++nt)
            bf[nt] = *(const short8*)&Wl[(w * 64 + nt * 16 + l15) * 72 + quad * 8 + ks * 32];
#pragma unroll
        for (int mt = 0; mt < 4; ++mt)
#pragma unroll
            for (int nt = 0; nt < 4; ++nt)
                acc[mt][nt] = __builtin_amdgcn_mfma_f32_16x16x32_bf16(af[mt], bf[nt], acc[mt][nt], 0, 0, 0);
    }

    for (int p = 0; p < 2; ++p) {
        __syncthreads();
        if ((w >> 1) == p) {
            float* tr = trans_s + (w & 1) * (64 * 68);
#pragma unroll
            for (int mt = 0; mt < 4; ++mt)
#pragma unroll
                for (int nt = 0; nt < 4; ++nt)
                    *(f32x4*)&tr[(nt * 16 + l15) * 68 + mt * 16 + quad * 4] = acc[mt][nt];
        }
        __syncthreads();
        for (int i = tid; i < 2048; i += 256) {
            int ol = i >> 4, tq = (i & 15) * 4;
            f32x4 v = *(const f32x4*)&trans_s[(ol >> 6) * (64 * 68) + (ol & 63) * 68 + tq];
            int o = p * 128 + ol;
            short4_t sv;
#pragma unroll
            for (int j = 0; j < 4; ++j) sv[j] = f2b(v[j]);
            int isel = o >> 6, h = (o >> 4) & 3, d = o & 15;
            *(short4_t*)&qkvvb[((size_t)(((isel * 2 + b) * 4 + h) * 16 + d) << 15) + n0 + tq] = sv;
        }
    }
}

// ------- merged MFMA: k/v projections + q.k logits + L2-norm accumulators -------
// rows: q = bh*16+d, k = 128+bh*16+d, v_sa = 384+bh*16+d (bf16, stride N)
__global__ __launch_bounds__(256) void k_pq(
    const short* __restrict__ qkvvb, const short* __restrict__ wefb,
    float* __restrict__ kp, float* __restrict__ vp, float* __restrict__ qd,
    float* __restrict__ qn_acc, float* __restrict__ kn_acc)
{
    int kc = blockIdx.x, bh = blockIdx.y;
    int tid = threadIdx.x;
    int w = tid >> 6, lane = tid & 63, l15 = lane & 15, quad = lane >> 4;
    size_t qrow = ((size_t)(bh * 16 + l15)) << 15;
    size_t krow = ((size_t)(128 + bh * 16 + l15)) << 15;
    size_t vrow = ((size_t)(384 + bh * 16 + l15)) << 15;
    int nbase = kc * 1024 + w * 256 + quad * 8;
    f32x4 acck[4], accv[4], accqd, accqq, acckk;
#pragma unroll
    for (int nt = 0; nt < 4; ++nt) {
        acck[nt] = (f32x4){0.f, 0.f, 0.f, 0.f};
        accv[nt] = (f32x4){0.f, 0.f, 0.f, 0.f};
    }
    accqd = (f32x4){0.f, 0.f, 0.f, 0.f};
    accqq = (f32x4){0.f, 0.f, 0.f, 0.f};
    acckk = (f32x4){0.f, 0.f, 0.f, 0.f};
#pragma unroll
    for (int ks = 0; ks < 8; ++ks) {
        int n = nbase + ks * 32;
        short8 qf = *(const short8*)&qkvvb[qrow + n];
        short8 kf = *(const short8*)&qkvvb[krow + n];
        short8 vf = *(const short8*)&qkvvb[vrow + n];
        accqd = __builtin_amdgcn_mfma_f32_16x16x32_bf16(qf, kf, accqd, 0, 0, 0);
        accqq = __builtin_amdgcn_mfma_f32_16x16x32_bf16(qf, qf, accqq, 0, 0, 0);
        acckk = __builtin_amdgcn_mfma_f32_16x16x32_bf16(kf, kf, acckk, 0, 0, 0);
#pragma unroll
        for (int nt = 0; nt < 4; ++nt) {
            short8 wf = *(const short8*)&wefb[(((size_t)(nt * 16 + l15)) << 15) + n];
            acck[nt] = __builtin_amdgcn_mfma_f32_16x16x32_bf16(kf, wf, acck[nt], 0, 0, 0);
            accv[nt] = __builtin_amdgcn_mfma_f32_16x16x32_bf16(vf, wf, accv[nt], 0, 0, 0);
        }
    }
    int d = quad * 4;
#pragma unroll
    for (int nt = 0; nt < 4; ++nt)
#pragma unroll
        for (int r = 0; r < 4; ++r) {
            int idx = (bh * 16 + d + r) * 64 + nt * 16 + l15;
            atomicAdd(&kp[idx], acck[nt][r]);
            atomicAdd(&vp[idx], accv[nt][r]);
        }
#pragma unroll
    for (int r = 0; r < 4; ++r)
        atomicAdd(&qd[bh * 256 + (d + r) * 16 + l15], accqd[r]);
    if (quad == (l15 >> 2)) {
        atomicAdd(&qn_acc[bh * 16 + l15], accqq[l15 & 3]);
        atomicAdd(&kn_acc[bh * 16 + l15], acckk[l15 & 3]);
    }
}

// ---------------- norm finalize + channel-attention softmax ----------------
__global__ void k_softmax_ca(const float* __restrict__ qd,
    const float* __restrict__ qn_acc, const float* __restrict__ kn_acc,
    const float* __restrict__ temp1, float* __restrict__ attn,
    float* __restrict__ iqn, float* __restrict__ ikn)
{
    __shared__ float iqs[128], iks[128];
    int tid = threadIdx.x;
    if (tid < 128) {
        float v = 1.f / fmaxf(sqrtf(qn_acc[tid]), 1e-12f);
        iqs[tid] = v; iqn[tid] = v;
    } else {
        int j = tid - 128;
        float v = 1.f / fmaxf(sqrtf(kn_acc[j]), 1e-12f);
        iks[j] = v; ikn[j] = v;
    }
    __syncthreads();
    int r = tid;
    if (r >= 128) return;
    int bh = r >> 4;
    int h = bh & 3;
    float iq = iqs[r];
    float t1 = temp1[h];
    float sc[16];
    float mx = -1e30f;
#pragma unroll
    for (int e = 0; e < 16; ++e) {
        float v = qd[r * 16 + e] * iq * iks[bh * 16 + e] * t1;
        sc[e] = v; mx = fmaxf(mx, v);
    }
    float s = 0.f;
#pragma unroll
    for (int e = 0; e < 16; ++e) { sc[e] = __expf(sc[e] - mx); s += sc[e]; }
    float inv = 1.f / s;
#pragma unroll
    for (int e = 0; e < 16; ++e) attn[r * 16 + e] = sc[e] * inv;
}

// ---------------- x_ca (v_ca bf16 rows at 256 + bh*16 + e) ----------------
__global__ __launch_bounds__(256) void k_xca(
    const short* __restrict__ qkvvb, const float* __restrict__ attn,
    float* __restrict__ xca)
{
    __shared__ float al[16][16];
    int bh = blockIdx.y; int b = bh >> 2, h = bh & 3;
    int tid = threadIdx.x;
    al[tid >> 4][tid & 15] = attn[bh * 256 + tid];
    __syncthreads();
    int n = blockIdx.x * 256 + tid;
    const short* vbase = qkvvb + (((size_t)(256 + bh * 16)) << 15) + n;
    float acc[16];
#pragma unroll
    for (int d = 0; d < 16; ++d) acc[d] = 0.f;
#pragma unroll
    for (int e = 0; e < 16; ++e) {
        float va = b2f(vbase[(size_t)e << 15]);
#pragma unroll
        for (int d = 0; d < 16; ++d) acc[d] += al[d][e] * va;
    }
    float* op = xca + ((size_t)(b * NTOK + n)) * 64 + h * 16;
#pragma unroll
    for (int d4 = 0; d4 < 4; ++d4) {
        float4 v; v.x = acc[d4 * 4]; v.y = acc[d4 * 4 + 1];
        v.z = acc[d4 * 4 + 2]; v.w = acc[d4 * 4 + 3];
        *(float4*)&op[d4 * 4] = v;
    }
}

// ---------------- fused spatial attention (q bf16) ----------------
__global__ __launch_bounds__(256) void k_attn_sa(
    const short* __restrict__ qkvvb, const float* __restrict__ inv_qn,
    const float* __restrict__ kp, const float* __restrict__ vp,
    const float* __restrict__ temp2, float* __restrict__ xsa)
{
    __shared__ float kl[16][64];
    __shared__ float vl[16][64];
    __shared__ float iq[16];
    int bh = blockIdx.y; int b = bh >> 2, h = bh & 3;
    int tid = threadIdx.x;
    for (int i = tid; i < 1024; i += 256) {
        kl[i >> 6][i & 63] = kp[bh * 1024 + i];
        vl[i >> 6][i & 63] = vp[bh * 1024 + i];
    }
    if (tid < 16) iq[tid] = inv_qn[bh * 16 + tid];
    __syncthreads();
    int n = blockIdx.x * 256 + tid;
    const short* qbase = qkvvb + (((size_t)(bh * 16)) << 15) + n;
    float qn_[16];
#pragma unroll
    for (int d = 0; d < 16; ++d) qn_[d] = b2f(qbase[(size_t)d << 15]) * iq[d];
    float t2 = temp2[h];
    float sc[64];
#pragma unroll
    for (int p = 0; p < 64; ++p) sc[p] = 0.f;
#pragma unroll
    for (int d = 0; d < 16; ++d) {
        float qv = qn_[d];
        const float4* kr = (const float4*)&kl[d][0];
#pragma unroll
        for (int p4 = 0; p4 < 16; ++p4) {
            float4 kv = kr[p4];
            sc[p4 * 4 + 0] += qv * kv.x; sc[p4 * 4 + 1] += qv * kv.y;
            sc[p4 * 4 + 2] += qv * kv.z; sc[p4 * 4 + 3] += qv * kv.w;
        }
    }
    float mx = -1e30f;
#pragma unroll
    for (int p = 0; p < 64; ++p) { sc[p] *= t2; mx = fmaxf(mx, sc[p]); }
    float s = 0.f;
#pragma unroll
    for (int p = 0; p < 64; ++p) { sc[p] = __expf(sc[p] - mx); s += sc[p]; }
    float inv = 1.f / s;
#pragma unroll
    for (int p = 0; p < 64; ++p) sc[p] *= inv;
    float* ob = xsa + (size_t)b * 2097152 + n;
#pragma unroll
    for (int d = 0; d < 16; ++d) {
        const float4* vr = (const float4*)&vl[d][0];
        float a0 = 0, a1 = 0, a2 = 0, a3 = 0;
#pragma unroll
        for (int p4 = 0; p4 < 16; ++p4) {
            float4 vv = vr[p4];
            a0 += sc[p4 * 4] * vv.x; a1 += sc[p4 * 4 + 1] * vv.y;
            a2 += sc[p4 * 4 + 2] * vv.z; a3 += sc[p4 * 4 + 3] * vv.w;
        }
        ob[(size_t)(d * 4 + h) * NTOK] = (a0 + a1) + (a2 + a3);
    }
}

// ---------------- EPA epilogue ----------------
__global__ __launch_bounds__(256) void k_epilogue(
    const float* __restrict__ x, const float* __restrict__ xsa,
    const float* __restrict__ xca, const float* __restrict__ Wo1,
    const float* __restrict__ bo1, const float* __restrict__ Wo2,
    const float* __restrict__ bo2, const float* __restrict__ gamma,
    float* __restrict__ attn_skip, short* __restrict__ gA)
{
    __shared__ float W1[32][64];
    __shared__ float W2[32][64];
    int tid = threadIdx.x;
    for (int i = tid; i < 2048; i += 256) {
        W1[i >> 6][i & 63] = Wo1[i];
        W2[i >> 6][i & 63] = Wo2[i];
    }
    __syncthreads();
    int bid = blockIdx.x;
    int b = bid >> 9;
    int n0 = (bid & 511) << 6;
    int t = tid & 63, cg = tid >> 6;
    int n = n0 + t;
    const float* row = (cg < 2) ? xsa + (size_t)b * 2097152 + (size_t)n * 64
                                : xca + ((size_t)(b * NTOK + n)) * 64;
    const float* Wb = (cg < 2) ? &W1[(cg & 1) * 16][0] : &W2[(cg & 1) * 16][0];
    const float* bias = (cg < 2) ? bo1 + (cg & 1) * 16 : bo2 + (cg & 1) * 16;
    float acc[16];
#pragma unroll
    for (int j = 0; j < 16; ++j) acc[j] = 0.f;
    const float4* r4 = (const float4*)row;
#pragma unroll
    for (int c4 = 0; c4 < 16; ++c4) {
        float4 rv = r4[c4];
#pragma unroll
        for (int j = 0; j < 16; ++j) {
            float4 wv = *(const float4*)&Wb[j * 64 + c4 * 4];
            acc[j] += rv.x * wv.x + rv.y * wv.y + rv.z * wv.z + rv.w * wv.w;
        }
    }
    float vals[16];
#pragma unroll
    for (int j = 0; j < 16; ++j) {
        int c = cg * 16 + j;
        size_t idx = (((size_t)(b * 64 + c)) << 15) + n;
        float v = x[idx] + gamma[c] * (acc[j] + bias[j]);
        attn_skip[idx] = v;
        vals[j] = v;
    }
    short8 lo, hi;
#pragma unroll
    for (int j = 0; j < 8; ++j) { lo[j] = f2b(vals[j]); hi[j] = f2b(vals[j + 8]); }
    short* gp = gA + ((size_t)(b * NTOK + n)) * 64 + cg * 16;
    *(short8*)&gp[0] = lo;
    *(short8*)&gp[8] = hi;
}

// ---------------- MFMA implicit-GEMM 3x3x3 conv (+fused conv8 in MODE 1) ----------------
template <int MODE>
__global__ __launch_bounds__(256) void k_conv3m(
    const short* __restrict__ gin, const short* __restrict__ wb,
    const float* __restrict__ bnw, const float* __restrict__ bnb,
    const float* __restrict__ skip, short* __restrict__ goutS,
    const short* __restrict__ wb8, const float* __restrict__ b8,
    float* __restrict__ io)
{
    __shared__ __align__(16) short inl_s[24480];
    __shared__ __align__(16) short wl_s[5120];
    __shared__ __align__(16) short a2_s[MODE ? 9216 : 16];
    int bx = blockIdx.x;
    int bb = bx >> 8;
    int z0 = (bx >> 3) & 31;
    int y0 = (bx & 7) * 4;
    int tid = threadIdx.x;
    int lane = tid & 63, wv = tid >> 6;
    int l15 = lane & 15, quad = lane >> 4;
    int wo = tid >> 2, wq = tid & 3;

    f32x4 acc[2][4];
#pragma unroll
    for (int s = 0; s < 2; ++s)
#pragma unroll
        for (int nt = 0; nt < 4; ++nt) acc[s][nt] = (f32x4){0.f, 0.f, 0.f, 0.f};

    int boff[4];
#pragma unroll
    for (int nt = 0; nt < 4; ++nt) boff[nt] = (nt * 16 + l15) * 40 + quad * 8;

    for (int chunk = 0; chunk < 2; ++chunk) {
        __syncthreads();
        for (int i = tid; i < 2448; i += 256) {
            int p = i >> 2, icq = i & 3;
            int xi = p % 34; int t2 = p / 34; int yi = t2 % 6; int zi = t2 / 6;
            int gz = z0 + zi - 1, gy = y0 + yi - 1, gx = xi - 1;
            short8 v = {0, 0, 0, 0, 0, 0, 0, 0};
            if ((unsigned)gz < 32u && (unsigned)gy < 32u && (unsigned)gx < 32u)
                v = *(const short8*)&gin[((size_t)(bb * NTOK + gz * 1024 + gy * 32 + gx)) * 64 + chunk * 32 + icq * 8];
            *(short8*)&inl_s[p * 40 + icq * 8] = v;
        }
        short8 wreg = *(const short8*)&wb[(size_t)wo * 64 + chunk * 32 + wq * 8];
        for (int tap = 0; tap < 27; ++tap) {
            *(short8*)&wl_s[(tap & 1) * 2560 + wo * 40 + wq * 8] = wreg;
            if (tap < 26)
                wreg = *(const short8*)&wb[(size_t)((tap + 1) * 64 + wo) * 64 + chunk * 32 + wq * 8];
            __syncthreads();
            int kz = tap / 9, ky = (tap / 3) % 3, kx = tap % 3;
            const short* wlb = &wl_s[(tap & 1) * 2560];
            short8 bf[4];
#pragma unroll
            for (int nt = 0; nt < 4; ++nt) bf[nt] = *(const short8*)&wlb[boff[nt]];
            int rowb = (kz * 6 + wv + ky) * 34;
#pragma unroll
            for (int s = 0; s < 2; ++s) {
                short8 af = *(const short8*)&inl_s[(rowb + s * 16 + l15 + kx) * 40 + quad * 8];
#pragma unroll
                for (int nt = 0; nt < 4; ++nt)
                    acc[s][nt] = __builtin_amdgcn_mfma_f32_16x16x32_bf16(af, bf[nt], acc[s][nt], 0, 0, 0);
            }
        }
    }
    __syncthreads();
    float rb = rsqrtf(1.f + 1e-5f);
    if (MODE == 0) {
        short* outS = inl_s;
#pragma unroll
        for (int nt = 0; nt < 4; ++nt) {
            int oc = nt * 16 + l15;
            float sc_ = bnw[oc] * rb, sh_ = bnb[oc];
#pragma unroll
            for (int s = 0; s < 2; ++s) {
                f32x4 v = acc[s][nt];
#pragma unroll
                for (int r = 0; r < 4; ++r) {
                    int pos = wv * 32 + s * 16 + quad * 4 + r;
                    float val = v[r] * sc_ + sh_;
                    val = val >= 0.f ? val : 0.01f * val;
                    outS[pos * 72 + oc] = f2b(val);
                }
            }
        }
        __syncthreads();
        for (int i = tid; i < 1024; i += 256) {
            int p = i >> 3, cq = i & 7;
            short8 v = *(const short8*)&outS[p * 72 + cq * 8];
            int y = p >> 5, x = p & 31;
            *(short8*)&goutS[((size_t)(bb * NTOK + z0 * 1024 + (y0 + y) * 32 + x)) * 64 + cq * 8] = v;
        }
    } else {
        float* outF = (float*)inl_s;
#pragma unroll
        for (int nt = 0; nt < 4; ++nt) {
            int oc = nt * 16 + l15;
#pragma unroll
            for (int s = 0; s < 2; ++s) {
                f32x4 v = acc[s][nt];
#pragma unroll
                for (int r = 0; r < 4; ++r) {
                    int pos = wv * 32 + s * 16 + quad * 4 + r;
                    outF[oc * 132 + pos] = v[r];
                }
            }
        }
        __syncthreads();
        f32x4 skr[8];
#pragma unroll
        for (int it = 0; it < 8; ++it) {
            int i = it * 256 + tid;
            int oc = i >> 5, xq = i & 31, pos0 = xq * 4;
            f32x4 c4 = *(const f32x4*)&outF[oc * 132 + pos0];
            int y = pos0 >> 5, xx = pos0 & 31;
            size_t g = (((size_t)(bb * 64 + oc)) << 15) + ((z0 * 32 + (y0 + y)) * 32 + xx);
            f32x4 sk = *(const f32x4*)&skip[g];
            skr[it] = sk;
            float sc_ = bnw[oc] * rb, sh_ = bnb[oc];
#pragma unroll
            for (int r = 0; r < 4; ++r) {
                float val = c4[r] * sc_ + sh_ + sk[r];
                val = val >= 0.f ? val : 0.01f * val;
                a2_s[(pos0 + r) * 72 + oc] = f2b(val);
            }
        }
        for (int i = tid; i < 512; i += 256) {
            int ocw = i >> 3, cq = i & 7;
            *(short8*)&wl_s[ocw * 80 + cq * 8] = *(const short8*)&wb8[ocw * 64 + cq * 8];
        }
        __syncthreads();
        f32x4 acc2[2][4];
#pragma unroll
        for (int s = 0; s < 2; ++s)
#pragma unroll
            for (int nt = 0; nt < 4; ++nt) acc2[s][nt] = (f32x4){0.f, 0.f, 0.f, 0.f};
#pragma unroll
        for (int ks = 0; ks < 2; ++ks) {
            short8 a8[2], b8f[4];
#pragma unroll
            for (int s = 0; s < 2; ++s)
                a8[s] = *(const short8*)&a2_s[(wv * 32 + s * 16 + l15) * 72 + quad * 8 + ks * 32];
#pragma unroll
            for (int nt = 0; nt < 4; ++nt)
                b8f[nt] = *(const short8*)&wl_s[(nt * 16 + l15) * 80 + quad * 8 + ks * 32];
#pragma unroll
            for (int s = 0; s < 2; ++s)
#pragma unroll
                for (int nt = 0; nt < 4; ++nt)
                    acc2[s][nt] = __builtin_amdgcn_mfma_f32_16x16x32_bf16(a8[s], b8f[nt], acc2[s][nt], 0, 0, 0);
        }
        __syncthreads();
#pragma unroll
        for (int nt = 0; nt < 4; ++nt) {
            int oc = nt * 16 + l15;
#pragma unroll
            for (int s = 0; s < 2; ++s) {
                f32x4 v = acc2[s][nt];
#pragma unroll
                for (int r = 0; r < 4; ++r) {
                    int pos = wv * 32 + s * 16 + quad * 4 + r;
                    outF[oc * 132 + pos] = v[r];
                }
            }
        }
        __syncthreads();
#pragma unroll
        for (int it = 0; it < 8; ++it) {
            int i = it * 256 + tid;
            int oc = i >> 5, xq = i & 31, pos0 = xq * 4;
            f32x4 cv = *(const f32x4*)&outF[oc * 132 + pos0];
            int y = pos0 >> 5, xx = pos0 & 31;
            size_t g = (((size_t)(bb * 64 + oc)) << 15) + ((z0 * 32 + (y0 + y)) * 32 + xx);
            float bias8 = b8[oc];
            f32x4 o;
#pragma unroll
            for (int r = 0; r < 4; ++r) o[r] = skr[it][r] + cv[r] + bias8;
            *(f32x4*)&io[g] = o;
        }
    }
}

extern "C" void kernel_launch(void* const* d_in, const int* in_sizes, int n_in,
                              void* d_out, int out_size, void* d_ws, size_t ws_size,
                              hipStream_t stream) {
    const float* x      = (const float*)d_in[0];
    const float* ln_w   = (const float*)d_in[1];
    const float* ln_b   = (const float*)d_in[2];
    const float* gamma  = (const float*)d_in[3];
    const float* temp1  = (const float*)d_in[4];
    const float* temp2  = (const float*)d_in[5];
    const float* W_qkvv = (const float*)d_in[6];
    const float* W_EF   = (const float*)d_in[7];
    const float* b_EF   = (const float*)d_in[8];
    const float* W_o1   = (const float*)d_in[9];
    const float* b_o1   = (const float*)d_in[10];
    const float* W_o2   = (const float*)d_in[11];
    const float* b_o2   = (const float*)d_in[12];
    const float* conv1w = (const float*)d_in[13];
    const float* conv2w = (const float*)d_in[14];
    const float* bn1_w  = (const float*)d_in[15];
    const float* bn1_b  = (const float*)d_in[16];
    const float* bn2_w  = (const float*)d_in[17];
    const float* bn2_b  = (const float*)d_in[18];
    const float* conv8w = (const float*)d_in[19];
    const float* conv8b = (const float*)d_in[20];

    float* ws    = (float*)d_ws;
    short* qkvvb = (short*)ws;               // 8388608 shorts (16 MB)
    float* buf1  = ws + 4194304;             // xca fp32
    float* buf2  = buf1 + 4194304;           // xsa fp32
    float* kp    = buf2 + 4194304;           // 8192
    float* vp    = kp + 8192;                // 8192
    float* qd    = vp + 8192;                // 2048
    float* qn_acc= qd + 2048;                // 128
    float* kn_acc= qn_acc + 128;             // 128
    float* a_ca  = kn_acc + 128;             // 2048
    float* iqn   = a_ca + 2048;              // 128
    float* ikn   = iqn + 128;                // 128
    short* gA    = (short*)(ikn + 128);      // 4194304 bf16
    short* g1    = gA + 4194304;             // 4194304 bf16
    short* wb1   = g1 + 4194304;             // 110592
    short* wb2   = wb1 + 110592;             // 110592
    short* wb8   = wb2 + 110592;             // 4096
    short* wefb  = wb8 + 4096;               // 2097152

    float* attn_skip = (float*)d_out;

    hipLaunchKernelGGL(k_init, dim3(32), dim3(256), 0, stream, b_EF, kp, vp, qd);
    hipLaunchKernelGGL(k_repack, dim3(9072), dim3(256), 0, stream,
                       conv1w, conv2w, conv8w, W_EF, wb1, wb2, wb8, wefb);
    hipLaunchKernelGGL(k_ln_qkvv, dim3(1024), dim3(256), 0, stream,
                       x, ln_w, ln_b, W_qkvv, qkvvb);
    hipLaunchKernelGGL(k_pq, dim3(32, 8), dim3(256), 0, stream,
                       qkvvb, wefb, kp, vp, qd, qn_acc, kn_acc);
    hipLaunchKernelGGL(k_softmax_ca, dim3(1), dim3(256), 0, stream,
                       qd, qn_acc, kn_acc, temp1, a_ca, iqn, ikn);
    hipLaunchKernelGGL(k_xca, dim3(128, 8), dim3(256), 0, stream, qkvvb, a_ca, buf1);
    hipLaunchKernelGGL(k_attn_sa, dim3(128, 8), dim3(256), 0, stream,
                       qkvvb, iqn, kp, vp, temp2, buf2);
    hipLaunchKernelGGL(k_epilogue, dim3(1024), dim3(256), 0, stream,
                       x, buf2, buf1, W_o1, b_o1, W_o2, b_o2, gamma, attn_skip, gA);
    hipLaunchKernelGGL((k_conv3m<0>), dim3(512), dim3(256), 0, stream,
                       gA, wb1, bn1_w, bn1_b, (const float*)nullptr, g1,
                       (const short*)nullptr, (const float*)nullptr, (float*)nullptr);
    hipLaunchKernelGGL((k_conv3m<1>), dim3(512), dim3(256), 0, stream,
                       g1, wb2, bn2_w, bn2_b, attn_skip, (short*)nullptr,
                       wb8, conv8b, attn_skip);
}